// Round 7
// baseline (9341.733 us; speedup 1.0000x reference)
//
#include <hip/hip_runtime.h>
#include <hip/hip_bf16.h>
#include <math.h>

typedef _Float16 fp16;
typedef _Float16 f16x8 __attribute__((ext_vector_type(8)));
typedef float f32x4 __attribute__((ext_vector_type(4)));

#define BB 16
#define PP 12
#define QQ 12
#define NN 2000
#define CC 1024

static __device__ __forceinline__ float ldf(float v) { return v; }
static __device__ __forceinline__ float ldf(fp16 v) { return (float)v; }
static __device__ __forceinline__ void stf(float* p, float v) { *p = v; }
static __device__ __forceinline__ void stf(fp16* p, float v) { *p = (fp16)v; }

// ---------- conversions / repacks ----------
__global__ void k_f2h(fp16* __restrict__ dst, const float* __restrict__ src, long long n) {
  long long i = (long long)blockIdx.x * 256 + threadIdx.x;
  if (i < n) dst[i] = (fp16)src[i];
}

// dcgru weights (512,O): row=f*4+t -> Wt[d][t*128+c] = src[(c*4+t)*O+d]
__global__ void k_gru_repackT(fp16* __restrict__ dst, const float* __restrict__ src, int O) {
  int i = blockIdx.x * 256 + threadIdx.x;
  if (i >= O * 512) return;
  int d = i >> 9;
  int kc = i & 511;
  int t = kc >> 7;
  int c = kc & 127;
  dst[i] = (fp16)src[(c * 4 + t) * O + d];
}

// (64,64) -> T[d][k] fp16
__global__ void k_w2T(fp16* __restrict__ dst, const float* __restrict__ src) {
  int i = blockIdx.x * 256 + threadIdx.x;
  if (i >= 4096) return;
  int d = i >> 6, k = i & 63;
  dst[i] = (fp16)src[k * 64 + d];
}

// ---------- laplacian (fp16, symmetric) ----------
__global__ void k_dinv(const float* __restrict__ adj, float* __restrict__ dinv) {
  int row = blockIdx.x;
  float s = 0.f;
  for (int j = threadIdx.x; j < NN; j += 256)
    s += fmaxf(adj[(long long)row * NN + j], adj[(long long)j * NN + row]);
  __shared__ float red[256];
  red[threadIdx.x] = s;
  __syncthreads();
  for (int st = 128; st > 0; st >>= 1) {
    if (threadIdx.x < st) red[threadIdx.x] += red[threadIdx.x + st];
    __syncthreads();
  }
  if (threadIdx.x == 0) {
    float d = red[0];
    dinv[row] = d > 0.f ? 1.0f / sqrtf(d) : 0.f;
  }
}

__global__ void k_L(const float* __restrict__ adj, const float* __restrict__ dinv,
                    fp16* __restrict__ Lh) {
  long long i = (long long)blockIdx.x * 256 + threadIdx.x;
  if (i >= (long long)NN * NN) return;
  int r = (int)(i / NN), c = (int)(i % NN);
  float a = fmaxf(adj[(long long)r * NN + c], adj[(long long)c * NN + r]);
  Lh[i] = (fp16)(-dinv[r] * a * dinv[c]);
}

// ---------- gumbel softmax -> fp16 ----------
__global__ void k_gumbel_softmax(const float* __restrict__ ml, const float* __restrict__ gn,
                                 fp16* __restrict__ mZ) {
  int row = blockIdx.x;
  __shared__ float buf[CC];
  __shared__ float red[256];
  int t = threadIdx.x;
  float mx = -1e30f;
  for (int j = t; j < CC; j += 256) {
    float u = gn[(long long)row * CC + j];
    float g = -logf(-logf(u + 1e-20f) + 1e-20f);
    float v = ml[(long long)row * CC + j] + g;
    buf[j] = v;
    mx = fmaxf(mx, v);
  }
  red[t] = mx;
  __syncthreads();
  for (int st = 128; st > 0; st >>= 1) {
    if (t < st) red[t] = fmaxf(red[t], red[t + st]);
    __syncthreads();
  }
  mx = red[0];
  __syncthreads();
  float s = 0.f;
  for (int j = t; j < CC; j += 256) {
    float e = expf(buf[j] - mx);
    buf[j] = e;
    s += e;
  }
  red[t] = s;
  __syncthreads();
  for (int st = 128; st > 0; st >>= 1) {
    if (t < st) red[t] += red[t + st];
    __syncthreads();
  }
  float inv = 1.0f / red[0];
  for (int j = t; j < CC; j += 256) mZ[(long long)row * CC + j] = (fp16)(buf[j] * inv);
}

__global__ void k_te(const int* __restrict__ TE, const float* __restrict__ w1,
                     const float* __restrict__ b1, float* __restrict__ tmp) {
  int i = blockIdx.x * 256 + threadIdx.x;
  if (i >= BB * PP * 64) return;
  int j = i & 63;
  int bp = i >> 6;
  int b = bp / PP, p = bp % PP;
  int te0 = TE[(b * (PP + QQ) + p) * 2 + 0];
  int te1 = TE[(b * (PP + QQ) + p) * 2 + 1];
  float v = w1[te0 * 64 + j] + w1[(7 + te1) * 64 + j] + b1[j];
  tmp[i] = fmaxf(v, 0.f);
}

__global__ void k_addb(float* __restrict__ dst, const float* __restrict__ b, int n) {
  int i = blockIdx.x * 256 + threadIdx.x;
  if (i < n) dst[i] += b[i & 63];
}

__global__ void k_zf1(const float* __restrict__ Z, const float* __restrict__ w1,
                      const float* __restrict__ b1, fp16* __restrict__ tmp) {
  long long i = (long long)blockIdx.x * 256 + threadIdx.x;
  if (i >= (long long)BB * PP * CC * 64) return;
  int j = (int)(i & 63);
  long long row = i >> 6;
  float v = Z[row * 2 + 0] * w1[j] + Z[row * 2 + 1] * w1[64 + j] + b1[j];
  tmp[i] = (fp16)fmaxf(v, 0.f);
}

__global__ void k_add_stez(fp16* __restrict__ Zf, const float* __restrict__ seZ,
                           const float* __restrict__ teZ) {
  long long i = (long long)blockIdx.x * 256 + threadIdx.x;
  if (i >= (long long)BB * PP * CC * 64) return;
  int j = (int)(i & 63);
  long long row = i >> 6;
  int c = (int)(row % CC);
  int bp = (int)(row / CC);
  Zf[i] = (fp16)((float)Zf[i] + seZ[c * 64 + j] + teZ[bp * 64 + j]);
}

// ---------- generic fp32-path GEMM (small ops) ----------
template <typename TA, typename TB, typename TC>
__global__ __launch_bounds__(256) void gemm_t(
    const TA* __restrict__ A, int lda, long long sA,
    const TB* __restrict__ Bm, int ldb, long long sB,
    TC* Cm, int ldc, long long sC,
    const TC* S, long long sS,
    const float* __restrict__ bias,
    int M, int Ncols, int K, float alpha, float beta, int act) {
  int bz = blockIdx.z;
  A += (long long)bz * sA;
  Bm += (long long)bz * sB;
  Cm += (long long)bz * sC;
  if (S) S += (long long)bz * sS;
  const int row0 = blockIdx.x * 64, col0 = blockIdx.y * 64;
  __shared__ float As[16][68];
  __shared__ float Bs[16][68];
  int tid = threadIdx.x, tx = tid & 15, ty = tid >> 4;
  float acc[4][4] = {};
  for (int k0 = 0; k0 < K; k0 += 16) {
#pragma unroll
    for (int j = 0; j < 4; ++j) {
      int e = tid + 256 * j;
      int m = e >> 4, kk = e & 15;
      int gm = row0 + m;
      As[kk][m] = (gm < M) ? ldf(A[(long long)gm * lda + k0 + kk]) : 0.f;
    }
#pragma unroll
    for (int j = 0; j < 4; ++j) {
      int e = tid + 256 * j;
      int kk = e >> 6, n = e & 63;
      int gn = col0 + n;
      Bs[kk][n] = (gn < Ncols) ? ldf(Bm[(long long)(k0 + kk) * ldb + gn]) : 0.f;
    }
    __syncthreads();
#pragma unroll
    for (int kk = 0; kk < 16; ++kk) {
      float a[4], bb[4];
#pragma unroll
      for (int i = 0; i < 4; ++i) a[i] = As[kk][ty * 4 + i];
#pragma unroll
      for (int j = 0; j < 4; ++j) bb[j] = Bs[kk][tx * 4 + j];
#pragma unroll
      for (int i = 0; i < 4; ++i)
#pragma unroll
        for (int j = 0; j < 4; ++j) acc[i][j] = fmaf(a[i], bb[j], acc[i][j]);
    }
    __syncthreads();
  }
#pragma unroll
  for (int i = 0; i < 4; ++i) {
    int r = row0 + ty * 4 + i;
    if (r >= M) continue;
#pragma unroll
    for (int j = 0; j < 4; ++j) {
      int cn = col0 + tx * 4 + j;
      if (cn >= Ncols) continue;
      float v = alpha * acc[i][j];
      if (bias) v += bias[cn];
      if (S) v += beta * ldf(S[(long long)r * ldc + cn]);
      if (act == 1) v = fmaxf(v, 0.f);
      else if (act == 2) v = 1.f / (1.f + expf(-v));
      else if (act == 3) v = tanhf(v);
      stf(&Cm[(long long)r * ldc + cn], v);
    }
  }
}

// ---------- mfma2: kept for weight GEMMs (B in [k][n] layout, slab-K) ----------
template <typename TC, int MT, bool BROW, bool TRANSC, bool BIASROW>
__global__ __launch_bounds__(256) void mfma2(
    const fp16* __restrict__ A, int lda, long long aBatch,
    const fp16* __restrict__ B, int ldb, long long bBatch, int bShift, long long bSlab,
    int bHi,
    TC* __restrict__ C, int ldc, long long cBatch,
    const TC* __restrict__ S, float beta,
    const float* __restrict__ bias, int biasBatch,
    const float* __restrict__ S2,
    int M, int Ncols, int K, float alpha, int act) {
  __shared__ fp16 As[MT][40];
  __shared__ fp16 Bs[64][40];
  const int z = blockIdx.z;
  const int gm0 = blockIdx.x * MT, n0 = blockIdx.y * 64;
  A += (long long)z * aBatch;
  B += (long long)z * bBatch;
  C += (long long)z * cBatch;
  if (S) S += (long long)z * cBatch;
  const int tid = threadIdx.x;
  const int lane = tid & 63, wv = tid >> 6;
  const int wr = wv >> 1, wc = wv & 1;
  const int quad = lane >> 4, ln = lane & 15;
  const unsigned bMask = (1u << bShift) - 1u;
  constexpr int WM = MT / 32;
  f32x4 acc[WM][2];
#pragma unroll
  for (int i = 0; i < WM; ++i)
#pragma unroll
    for (int j = 0; j < 2; ++j) acc[i][j] = (f32x4){0.f, 0.f, 0.f, 0.f};

  for (int k0 = 0; k0 < K; k0 += 32) {
#pragma unroll
    for (int i = 0; i < MT / 64; ++i) {
      int c = tid + 256 * i;
      int row = c >> 2, seg = c & 3;
      int gm = gm0 + row;
      int kk0 = k0 + seg * 8;
      const fp16* src = A + (long long)gm * lda + kk0;
      if (gm < M && kk0 + 8 <= K) {
        *(f16x8*)&As[row][seg * 8] = *(const f16x8*)src;
      } else {
#pragma unroll
        for (int j = 0; j < 8; ++j)
          As[row][seg * 8 + j] = (gm < M && kk0 + j < K) ? src[j] : (fp16)0.f;
      }
    }
    if (BROW) {
      int n = tid >> 2, seg = tid & 3;
      int gn = n0 + n;
      int kk0 = k0 + seg * 8;
      const fp16* src = B + (long long)gn * ldb + kk0;
      if (gn < Ncols && kk0 + 8 <= K) {
        *(f16x8*)&Bs[n][seg * 8] = *(const f16x8*)src;
      } else {
#pragma unroll
        for (int j = 0; j < 8; ++j)
          Bs[n][seg * 8 + j] = (gn < Ncols && kk0 + j < K) ? src[j] : (fp16)0.f;
      }
    } else {
      int kk = k0 + (tid & 31);
      int ngrp = tid >> 5;
      int slab = (int)((unsigned)kk >> bShift);
      int kin = (int)((unsigned)kk & bMask);
      int col = kin + (kin >= 64 ? bHi : 0);
      int n = n0 + ngrp * 8;
      const fp16* src = B + (long long)slab * bSlab + (long long)col * ldb + n;
      if (kk < K && n + 8 <= Ncols) {
        f16x8 v = *(const f16x8*)src;
#pragma unroll
        for (int j = 0; j < 8; ++j) Bs[ngrp * 8 + j][tid & 31] = v[j];
      } else {
#pragma unroll
        for (int j = 0; j < 8; ++j)
          Bs[ngrp * 8 + j][tid & 31] = (kk < K && n + j < Ncols) ? src[j] : (fp16)0.f;
      }
    }
    __syncthreads();
    f16x8 af[WM], bf[2];
#pragma unroll
    for (int wm = 0; wm < WM; ++wm)
      af[wm] = *(const f16x8*)&As[wr * (MT / 2) + wm * 16 + ln][quad * 8];
#pragma unroll
    for (int wn = 0; wn < 2; ++wn)
      bf[wn] = *(const f16x8*)&Bs[wc * 32 + wn * 16 + ln][quad * 8];
#pragma unroll
    for (int wm = 0; wm < WM; ++wm)
#pragma unroll
      for (int wn = 0; wn < 2; ++wn)
        acc[wm][wn] =
            __builtin_amdgcn_mfma_f32_16x16x32_f16(af[wm], bf[wn], acc[wm][wn], 0, 0, 0);
    __syncthreads();
  }
#pragma unroll
  for (int wm = 0; wm < WM; ++wm) {
#pragma unroll
    for (int wn = 0; wn < 2; ++wn) {
#pragma unroll
      for (int r = 0; r < 4; ++r) {
        int gm = gm0 + wr * (MT / 2) + wm * 16 + quad * 4 + r;
        int gn = n0 + wc * 32 + wn * 16 + ln;
        if (gm < M && gn < Ncols) {
          float v = alpha * acc[wm][wn][r];
          if (bias) v += BIASROW ? bias[gm] : bias[(long long)z * biasBatch + gn];
          if (S2) v += S2[(long long)gm * 64 + gn];
          long long ci = TRANSC ? ((long long)gn * ldc + gm) : ((long long)gm * ldc + gn);
          if (S) v += beta * ldf(S[ci]);
          if (act == 1) v = fmaxf(v, 0.f);
          else if (act == 2) v = 1.f / (1.f + expf(-v));
          else if (act == 3) v = tanhf(v);
          stf(&C[ci], v);
        }
      }
    }
  }
}

// ---------- mfma3: all-b128 GEMM, templated tiles, M-slab row mapping ----------
// C = act(alpha*A@B^T + rowBias + s2T + beta*S)   (B given as rows [n][k])
// A row ptr  = A + zA*z + (gm>>aMsh)*aMslab + (gm&aMmask)*lda
// C/S row off= (gm>>cMsh)*cMslab + (gm&cMmask)*ldc
template <int MT, int NT>
__global__ __launch_bounds__(256) void mfma3(
    const fp16* __restrict__ A, int lda, long long zA, int aMsh, long long aMslab,
    const fp16* __restrict__ B, int ldb, long long zB,
    fp16* __restrict__ C, int ldc, long long zC, int cMsh, long long cMslab,
    const fp16* __restrict__ S, long long zS, float beta,
    const float* __restrict__ rowBias, long long zRB,
    const float* __restrict__ s2T, int s2ld,
    int M, int Ncols, int K, float alpha, int act) {
  __shared__ fp16 As[MT][40];
  __shared__ fp16 Bs[NT][40];
  const int z = blockIdx.z;
  const int gm0 = blockIdx.x * MT, n0 = blockIdx.y * NT;
  A += (long long)z * zA;
  B += (long long)z * zB;
  C += (long long)z * zC;
  if (S) S += (long long)z * zS;
  const int tid = threadIdx.x;
  const int lane = tid & 63, wv = tid >> 6;
  const int wr = wv >> 1, wc = wv & 1;
  const int quad = lane >> 4, ln = lane & 15;
  const unsigned aMmask = (1u << aMsh) - 1u;
  const unsigned cMmask = (1u << cMsh) - 1u;
  constexpr int WM = MT / 32, WN = NT / 32;
  f32x4 acc[WM][WN];
#pragma unroll
  for (int i = 0; i < WM; ++i)
#pragma unroll
    for (int j = 0; j < WN; ++j) acc[i][j] = (f32x4){0.f, 0.f, 0.f, 0.f};

  for (int k0 = 0; k0 < K; k0 += 32) {
#pragma unroll
    for (int i = 0; i < MT / 64; ++i) {
      int c = tid + 256 * i;
      int row = c >> 2, seg = c & 3;
      int gm = gm0 + row;
      int kk0 = k0 + seg * 8;
      const fp16* src = A + ((long long)((unsigned)gm >> aMsh)) * aMslab +
                        (long long)(gm & aMmask) * lda + kk0;
      if (gm < M && kk0 + 8 <= K) {
        *(f16x8*)&As[row][seg * 8] = *(const f16x8*)src;
      } else {
#pragma unroll
        for (int j = 0; j < 8; ++j)
          As[row][seg * 8 + j] = (gm < M && kk0 + j < K) ? src[j] : (fp16)0.f;
      }
    }
#pragma unroll
    for (int i = 0; i < NT / 64; ++i) {
      int c = tid + 256 * i;
      int n = c >> 2, seg = c & 3;
      int gn = n0 + n;
      int kk0 = k0 + seg * 8;
      const fp16* src = B + (long long)gn * ldb + kk0;
      if (gn < Ncols && kk0 + 8 <= K) {
        *(f16x8*)&Bs[n][seg * 8] = *(const f16x8*)src;
      } else {
#pragma unroll
        for (int j = 0; j < 8; ++j)
          Bs[n][seg * 8 + j] = (gn < Ncols && kk0 + j < K) ? src[j] : (fp16)0.f;
      }
    }
    __syncthreads();
    f16x8 af[WM], bf[WN];
#pragma unroll
    for (int wm = 0; wm < WM; ++wm)
      af[wm] = *(const f16x8*)&As[wr * (MT / 2) + wm * 16 + ln][quad * 8];
#pragma unroll
    for (int wn = 0; wn < WN; ++wn)
      bf[wn] = *(const f16x8*)&Bs[wc * (NT / 2) + wn * 16 + ln][quad * 8];
#pragma unroll
    for (int wm = 0; wm < WM; ++wm)
#pragma unroll
      for (int wn = 0; wn < WN; ++wn)
        acc[wm][wn] =
            __builtin_amdgcn_mfma_f32_16x16x32_f16(af[wm], bf[wn], acc[wm][wn], 0, 0, 0);
    __syncthreads();
  }
#pragma unroll
  for (int wm = 0; wm < WM; ++wm) {
#pragma unroll
    for (int wn = 0; wn < WN; ++wn) {
#pragma unroll
      for (int r = 0; r < 4; ++r) {
        int gm = gm0 + wr * (MT / 2) + wm * 16 + quad * 4 + r;
        int gn = n0 + wc * (NT / 2) + wn * 16 + ln;
        if (gm < M && gn < Ncols) {
          float v = alpha * acc[wm][wn][r];
          if (rowBias) v += rowBias[(long long)z * zRB + gm];
          if (s2T) v += s2T[(long long)gn * s2ld + gm];
          long long ci = ((long long)((unsigned)gm >> cMsh)) * cMslab +
                         (long long)(gm & cMmask) * ldc + gn;
          if (S) v += beta * (float)S[ci];
          if (act == 1) v = fmaxf(v, 0.f);
          else if (act == 2) v = 1.f / (1.f + expf(-v));
          else if (act == 3) v = tanhf(v);
          C[ci] = (fp16)v;
        }
      }
    }
  }
}

// ---------- ConvLSTM conv as MFMA ----------
__global__ __launch_bounds__(256) void k_conv_mfma(
    const fp16* __restrict__ Zf, const fp16* __restrict__ h,
    const fp16* __restrict__ wcat, fp16* __restrict__ gates, int p) {
  __shared__ fp16 As[128][40];
  __shared__ fp16 Bs[64][40];
  const int gm0 = blockIdx.x * 128, n0 = blockIdx.y * 64;
  const int tid = threadIdx.x;
  const int lane = tid & 63, wv = tid >> 6;
  const int wr = wv >> 1, wc = wv & 1;
  const int quad = lane >> 4, ln = lane & 15;
  f32x4 acc[4][2];
#pragma unroll
  for (int i = 0; i < 4; ++i)
#pragma unroll
    for (int j = 0; j < 2; ++j) acc[i][j] = (f32x4){0.f, 0.f, 0.f, 0.f};

  for (int kb = 0; kb < 36; ++kb) {
    const int srcsel = kb >= 18;
    const int tap = (kb >> 1) % 9;
    const int half = kb & 1;
    const int dy = tap / 3 - 1, dx = tap % 3 - 1;
#pragma unroll
    for (int i = 0; i < 2; ++i) {
      int c = tid + 256 * i;
      int row = c >> 2, seg = c & 3;
      int m = gm0 + row;
      int b = m >> 10;
      int y = (m >> 5) & 31, x = m & 31;
      int yy = y + dy, xx = x + dx;
      bool valid = ((unsigned)yy < 32u) && ((unsigned)xx < 32u);
      f16x8 v;
      if (valid) {
        long long cell = ((long long)b << 10) + (yy << 5) + xx;
        const fp16* sp =
            srcsel ? (h + cell * 64)
                   : (Zf + ((((long long)(b * PP + p)) << 10) + (yy << 5) + xx) * 64);
        v = *(const f16x8*)(sp + half * 32 + seg * 8);
      } else {
#pragma unroll
        for (int j = 0; j < 8; ++j) v[j] = (fp16)0.f;
      }
      *(f16x8*)&As[row][seg * 8] = v;
    }
    {
      int kk = kb * 32 + (tid & 31);
      int ngrp = tid >> 5;
      int n = n0 + ngrp * 8;
      f16x8 v = *(const f16x8*)(wcat + (long long)kk * 256 + n);
#pragma unroll
      for (int j = 0; j < 8; ++j) Bs[ngrp * 8 + j][tid & 31] = v[j];
    }
    __syncthreads();
    f16x8 af[4], bf[2];
#pragma unroll
    for (int wm = 0; wm < 4; ++wm)
      af[wm] = *(const f16x8*)&As[wr * 64 + wm * 16 + ln][quad * 8];
#pragma unroll
    for (int wn = 0; wn < 2; ++wn)
      bf[wn] = *(const f16x8*)&Bs[wc * 32 + wn * 16 + ln][quad * 8];
#pragma unroll
    for (int wm = 0; wm < 4; ++wm)
#pragma unroll
      for (int wn = 0; wn < 2; ++wn)
        acc[wm][wn] =
            __builtin_amdgcn_mfma_f32_16x16x32_f16(af[wm], bf[wn], acc[wm][wn], 0, 0, 0);
    __syncthreads();
  }
#pragma unroll
  for (int wm = 0; wm < 4; ++wm)
#pragma unroll
    for (int wn = 0; wn < 2; ++wn)
#pragma unroll
      for (int r = 0; r < 4; ++r) {
        int gm = gm0 + wr * 64 + wm * 16 + quad * 4 + r;
        int gn = n0 + wc * 32 + wn * 16 + ln;
        gates[(long long)gm * 256 + gn] = (fp16)acc[wm][wn][r];
      }
}

// update; h kept [cell][64]; ZclT written transposed [bp][d][cell]
__global__ void k_clstm_update(const fp16* __restrict__ gates, float* __restrict__ c,
                               fp16* __restrict__ h, fp16* __restrict__ ZclT, int p) {
  long long i = (long long)blockIdx.x * 256 + threadIdx.x;
  if (i >= (long long)BB * CC * 64) return;
  int d = (int)(i & 63);
  long long bc = i >> 6;
  int b = (int)(bc >> 10);
  int cell = (int)(bc & 1023);
  const fp16* g = gates + (((long long)b * CC) + cell) * 256;
  float gi = (float)g[d], gf = (float)g[64 + d], gg = (float)g[128 + d],
        go = (float)g[192 + d];
  float hs_f = fminf(fmaxf(0.2f * gf + 0.5f, 0.f), 1.f);
  float hs_i = fminf(fmaxf(0.2f * gi + 0.5f, 0.f), 1.f);
  float hs_o = fminf(fmaxf(0.2f * go + 0.5f, 0.f), 1.f);
  float cv = hs_f * c[i] + hs_i * tanhf(gg);
  c[i] = cv;
  float hv = hs_o * tanhf(cv);
  h[i] = (fp16)hv;
  ZclT[(((long long)(b * PP + p)) * 64 + d) * CC + cell] = (fp16)hv;
}

// Tmat[row][j] = relu(X[row]*w1[j]+b1[j]) fp16
__global__ void k_tmat(const float* __restrict__ X, const float* __restrict__ w1,
                       const float* __restrict__ b1, fp16* __restrict__ T) {
  long long i = (long long)blockIdx.x * 256 + threadIdx.x;
  if (i >= (long long)BB * PP * NN * 64) return;
  int j = (int)(i & 63);
  long long row = i >> 6;
  T[i] = (fp16)fmaxf(X[row] * w1[j] + b1[j], 0.f);
}

// ---------- DCGRU elementwise (all fp16 h) ----------
__global__ void k_u0T(const fp16* __restrict__ ZXt, const fp16* __restrict__ hgH,
                      fp16* __restrict__ U0, int p) {
  long long i = (long long)blockIdx.x * 256 + threadIdx.x;  // vec8 over n
  if (i >= (long long)BB * 128 * (NN / 8)) return;
  int n8 = (int)(i % (NN / 8));
  int c = (int)((i / (NN / 8)) & 127);
  int b = (int)(i / ((NN / 8) * 128));
  f16x8 v;
  if (c < 64)
    v = *(const f16x8*)(ZXt + ((((long long)(b * PP + p)) * 64 + c) * NN) + n8 * 8);
  else
    v = *(const f16x8*)(hgH + (long long)(c - 64) * (BB * NN) + b * NN + n8 * 8);
  *(f16x8*)(U0 + ((long long)b * 192 + c) * NN + n8 * 8) = v;
}

__global__ void k_u0cT(const float* __restrict__ ruT, const fp16* __restrict__ hgH,
                       fp16* __restrict__ U0) {
  long long i = (long long)blockIdx.x * 256 + threadIdx.x;
  if (i >= (long long)BB * 64 * NN) return;
  int n = (int)(i % NN);
  int d = (int)((i / NN) & 63);
  int b = (int)(i / (NN * 64));
  float r = ruT[((long long)b * 128 + d) * NN + n];
  float h = (float)hgH[(long long)d * (BB * NN) + b * NN + n];
  U0[((long long)b * 192 + 128 + d) * NN + n] = (fp16)(r * h);
}

__global__ void k_h_updT(fp16* __restrict__ hgH, const float* __restrict__ ruT,
                         const float* __restrict__ cndT) {
  long long i = (long long)blockIdx.x * 256 + threadIdx.x;
  if (i >= (long long)BB * 64 * NN) return;
  int n = (int)(i % NN);
  int d = (int)((i / NN) & 63);
  int b = (int)(i / (NN * 64));
  float u = ruT[((long long)b * 128 + 64 + d) * NN + n];
  long long hi = (long long)d * (BB * NN) + b * NN + n;
  float cn = cndT[((long long)b * 64 + d) * NN + n];
  hgH[hi] = (fp16)(u * (float)hgH[hi] + (1.f - u) * cn);
}

__global__ void k_trT(const fp16* __restrict__ hgH, float* __restrict__ htmp) {
  long long i = (long long)blockIdx.x * 256 + threadIdx.x;
  if (i >= (long long)BB * NN * 64) return;
  int d = (int)(i & 63);
  long long bn = i >> 6;
  htmp[i] = (float)hgH[(long long)d * (BB * NN) + bn];
}

__global__ void k_out(const float* __restrict__ Y, float* __restrict__ out) {
  int i = blockIdx.x * 256 + threadIdx.x;
  if (i >= BB * QQ * NN) return;
  int n = i % NN;
  int bq = i / NN;
  int b = bq / QQ, q = bq % QQ;
  out[i] = Y[((long long)b * NN + n) * 12 + q];
}

// ---------- host helpers ----------
template <typename TA, typename TB, typename TC>
static void launch_gemm(hipStream_t stream, const TA* A, int lda, long long sA,
                        const TB* Bm, int ldb, long long sB, TC* Cm, int ldc, long long sC,
                        const TC* S, long long sS, const float* bias, int M, int Nc, int K,
                        float alpha, float beta, int act, int batch) {
  dim3 g((M + 63) / 64, (Nc + 63) / 64, batch);
  gemm_t<TA, TB, TC><<<g, dim3(256), 0, stream>>>(A, lda, sA, Bm, ldb, sB, Cm, ldc, sC, S,
                                                  sS, bias, M, Nc, K, alpha, beta, act);
}

extern "C" void kernel_launch(void* const* d_in, const int* in_sizes, int n_in,
                              void* d_out, int out_size, void* d_ws, size_t ws_size,
                              hipStream_t stream) {
  char* base = (char*)d_ws;
  size_t off = 0;
  auto alloc_bytes = [&](size_t nb) -> char* {
    char* p = base + off;
    off += (nb + 255) & ~(size_t)255;
    return p;
  };
  auto allocf = [&](size_t n) -> float* { return (float*)alloc_bytes(n * 4); };
  auto alloch = [&](size_t n) -> fp16* { return (fp16*)alloc_bytes(n * 2); };

  const float* X = (const float*)d_in[0];
  const float* Z = (const float*)d_in[1];
  const int* TE = (const int*)d_in[2];
  const float* adj_gg = (const float*)d_in[3];
  const float* adj_gr = (const float*)d_in[4];
  const float* gumbel = (const float*)d_in[5];
  const float* se_x = (const float*)d_in[6];
  const float* se_z = (const float*)d_in[7];
  const float* movement = (const float*)d_in[8];
  auto W = [&](int i) { return (const float*)d_in[i]; };

  // ---- allocations ----
  fp16* wcat = alloch(1152 * 256);
  fp16* gwT = alloch(128 * 512);
  fp16* cwT = alloch(64 * 512);
  fp16* w2T = alloch(64 * 64);   // fcs_x_in_w2^T
  fp16* w2mT = alloch(64 * 64);  // mov_fc_w^T
  float* dinv = allocf(NN);
  fp16* Lh = alloch((size_t)NN * NN);
  fp16* mZh = alloch((size_t)CC * CC);
  fp16* agh2 = alloch((size_t)NN * CC);  // adj_gr native [n][c]
  float* seZ = allocf(CC * 64);
  float* teZ = allocf(BB * PP * 64);
  float* seX = allocf(NN * 64);
  float* teXb = allocf(BB * PP * 64);
  float* mtmp = allocf(NN * 64);
  float* tetmp = allocf(BB * PP * 64);
  fp16* hgH = alloch((size_t)64 * BB * NN);    // [64 d][b*2000+n]
  float* ruT = allocf((size_t)BB * 128 * NN);  // [b][128][2000]
  float* cndT = allocf((size_t)BB * 64 * NN);  // [b][64][2000]
  // big pool: U slabs (49.15MB) | Zmix(25.2)+ZmovT(25.2) | gates/chh/ccc | Tmat | htmp
  const long long SLAB = (long long)BB * 192 * NN;  // 6,144,000 elem
  char* pool = alloc_bytes(50331648);
  fp16* Uall = (fp16*)pool;
  fp16* gates = (fp16*)pool;
  fp16* chh = (fp16*)(pool + 8388608);
  float* ccc = (float*)(pool + 12582912);
  fp16* Zmix = (fp16*)pool;                 // [bp][1024][64]
  fp16* ZmovT = (fp16*)(pool + 25165824);   // [bp][64][1024]
  fp16* Tmat = (fp16*)pool;                 // [bp*2000][64]
  float* htmp = (float*)pool;
  // zpool: Zf [bp][1024][64] then ZXt [bp][64][2000]
  fp16* zpool = alloch((size_t)BB * PP * NN * 64);
  fp16* Zf = zpool;
  fp16* ZXt = zpool;
  fp16* Zc = alloch((size_t)BB * PP * CC * 64);  // zf1 scratch, then ZclT [bp][64][1024]

  if (off > ws_size) return;  // soft-fail diagnostic

  // ---- precompute ----
  k_f2h<<<dim3(576), dim3(256), 0, stream>>>(wcat, W(39), 576 * 256);
  k_f2h<<<dim3(576), dim3(256), 0, stream>>>(wcat + 576 * 256, W(40), 576 * 256);
  k_gru_repackT<<<dim3(256), dim3(256), 0, stream>>>(gwT, W(41), 128);
  k_gru_repackT<<<dim3(128), dim3(256), 0, stream>>>(cwT, W(43), 64);
  k_w2T<<<dim3(16), dim3(256), 0, stream>>>(w2T, W(31));
  k_w2T<<<dim3(16), dim3(256), 0, stream>>>(w2mT, W(33));
  k_dinv<<<dim3(NN), dim3(256), 0, stream>>>(adj_gg, dinv);
  k_L<<<dim3((NN * NN + 255) / 256), dim3(256), 0, stream>>>(adj_gg, dinv, Lh);
  k_gumbel_softmax<<<dim3(CC), dim3(256), 0, stream>>>(movement, gumbel, mZh);
  k_f2h<<<dim3((NN * CC + 255) / 256), dim3(256), 0, stream>>>(agh2, adj_gr,
                                                               (long long)NN * CC);

  // ---- STEZ / STEX ----
  launch_gemm(stream, se_z, 64, 0LL, W(17), 64, 0LL, mtmp, 64, 0LL, (float*)nullptr, 0LL,
              W(18), CC, 64, 64, 1.f, 0.f, 1, 1);
  launch_gemm(stream, (const float*)mtmp, 64, 0LL, W(19), 64, 0LL, seZ, 64, 0LL,
              (float*)nullptr, 0LL, W(20), CC, 64, 64, 1.f, 0.f, 0, 1);
  k_te<<<dim3((BB * PP * 64 + 255) / 256), dim3(256), 0, stream>>>(TE, W(21), W(22), tetmp);
  launch_gemm(stream, (const float*)tetmp, 64, 0LL, W(23), 64, 0LL, teZ, 64, 0LL,
              (float*)nullptr, 0LL, W(24), BB * PP, 64, 64, 1.f, 0.f, 0, 1);
  launch_gemm(stream, se_x, 64, 0LL, W(9), 64, 0LL, mtmp, 64, 0LL, (float*)nullptr, 0LL,
              W(10), NN, 64, 64, 1.f, 0.f, 1, 1);
  launch_gemm(stream, (const float*)mtmp, 64, 0LL, W(11), 64, 0LL, seX, 64, 0LL,
              (float*)nullptr, 0LL, W(12), NN, 64, 64, 1.f, 0.f, 0, 1);
  k_te<<<dim3((BB * PP * 64 + 255) / 256), dim3(256), 0, stream>>>(TE, W(13), W(14), tetmp);
  launch_gemm(stream, (const float*)tetmp, 64, 0LL, W(15), 64, 0LL, teXb, 64, 0LL,
              (float*)nullptr, 0LL, W(16), BB * PP, 64, 64, 1.f, 0.f, 0, 1);
  k_addb<<<dim3((BB * PP * 64 + 255) / 256), dim3(256), 0, stream>>>(teXb, W(32),
                                                                     BB * PP * 64);

  // ---- Zf = mlp2(Z) + STEZ ----
  long long nZ = (long long)BB * PP * CC * 64;
  k_zf1<<<dim3((int)((nZ + 255) / 256)), dim3(256), 0, stream>>>(Z, W(25), W(26), Zc);
  launch_gemm(stream, (const fp16*)Zc, 64, 0LL, W(27), 64, 0LL, Zf, 64, 0LL,
              (fp16*)nullptr, 0LL, W(28), BB * PP * CC, 64, 64, 1.f, 0.f, 0, 1);
  k_add_stez<<<dim3((int)((nZ + 255) / 256)), dim3(256), 0, stream>>>(Zf, seZ, teZ);

  // ---- ConvLSTM (writes ZclT into Zc) ----
  hipMemsetAsync(chh, 0, (size_t)BB * CC * 64 * 2, stream);
  hipMemsetAsync(ccc, 0, (size_t)BB * CC * 64 * 4, stream);
  for (int p = 0; p < PP; ++p) {
    k_conv_mfma<<<dim3(BB * CC / 128, 4), dim3(256), 0, stream>>>(Zf, chh, wcat, gates, p);
    k_clstm_update<<<dim3((int)(((long long)BB * CC * 64 + 255) / 256)), dim3(256), 0,
                     stream>>>(gates, ccc, chh, Zc, p);
  }

  // ---- movement chain (all-b128) ----
  // m1: Zmix[c][d] = mZ @ ZclT^T  (M=1024, N=64, K=1024, z=192)
  mfma3<128, 64><<<dim3(8, 1, 192), dim3(256), 0, stream>>>(
      mZh, CC, 0LL, 31, 0LL, (const fp16*)Zc, CC, (long long)64 * CC, Zmix, 64,
      (long long)CC * 64, 31, 0LL, (const fp16*)nullptr, 0LL, 0.f, nullptr, 0LL, nullptr,
      0, CC, 64, CC, 1.f, 0);
  // m2: ZmovT[d'][c] = relu(w2m^T @ Zmix^T + b)  (M=64, N=1024, K=64, z=192)
  mfma3<64, 128><<<dim3(1, 8, 192), dim3(256), 0, stream>>>(
      w2mT, 64, 0LL, 31, 0LL, Zmix, 64, (long long)CC * 64, ZmovT, CC,
      (long long)64 * CC, 31, 0LL, (const fp16*)nullptr, 0LL, 0.f, W(34), 0LL, nullptr, 0,
      64, CC, 64, 1.f, 1);
  // m3: ZXt[d][n] = ZmovT @ adj_gr^T + teXb[bp][d] + seX[n][d]  (M=64,N=2000,K=1024)
  mfma3<64, 128><<<dim3(1, 16, 192), dim3(256), 0, stream>>>(
      ZmovT, CC, (long long)64 * CC, 31, 0LL, agh2, CC, 0LL, ZXt, NN, (long long)64 * NN,
      31, 0LL, (const fp16*)nullptr, 0LL, 0.f, teXb, 64LL, seX, 64, 64, NN, CC, 1.f, 0);

  // ---- ZXt += (relu(X*w1+b1) @ w2)^T via w2T @ Tmat^T ----
  k_tmat<<<dim3((int)(((long long)BB * PP * NN * 64 + 255) / 256)), dim3(256), 0, stream>>>(
      X, W(29), W(30), Tmat);
  mfma3<64, 128><<<dim3(1, 16, 192), dim3(256), 0, stream>>>(
      w2T, 64, 0LL, 31, 0LL, Tmat, 64, (long long)NN * 64, ZXt, NN, (long long)64 * NN, 31,
      0LL, (const fp16*)ZXt, (long long)64 * NN, 1.f, nullptr, 0LL, nullptr, 0, 64, NN, 64,
      1.f, 0);

  // ---- DCGRU ----
  hipMemsetAsync(hgH, 0, (size_t)64 * BB * NN * 2, stream);
  fp16* U0 = Uall;
  fp16* U1 = Uall + SLAB;
  fp16* U2 = Uall + 2 * SLAB;
  fp16* U3 = Uall + 3 * SLAB;
  const long long uB = (long long)192 * NN;  // per-b stride within a slab
  const long long nU0 = (long long)BB * 128 * (NN / 8);
  const long long n64 = (long long)BB * 64 * NN;
  for (int p = 0; p < PP; ++p) {
    // gate chain: fused M=2048 rows (b,[x|h]) via slab mapping (sh=7, slab=uB)
    k_u0T<<<dim3((int)((nU0 + 255) / 256)), dim3(256), 0, stream>>>(ZXt, hgH, U0, p);
    mfma3<128, 128><<<dim3(16, 16, 1), dim3(256), 0, stream>>>(
        U0, NN, 0LL, 7, uB, Lh, NN, 0LL, U1, NN, 0LL, 7, uB, (const fp16*)nullptr, 0LL,
        0.f, nullptr, 0LL, nullptr, 0, 2048, NN, NN, 1.f, 0);
    mfma3<128, 128><<<dim3(16, 16, 1), dim3(256), 0, stream>>>(
        U1, NN, 0LL, 7, uB, Lh, NN, 0LL, U2, NN, 0LL, 7, uB, (const fp16*)U0, 0LL, -1.f,
        nullptr, 0LL, nullptr, 0, 2048, NN, NN, 2.f, 0);
    mfma3<128, 128><<<dim3(16, 16, 1), dim3(256), 0, stream>>>(
        U2, NN, 0LL, 7, uB, Lh, NN, 0LL, U3, NN, 0LL, 7, uB, (const fp16*)U1, 0LL, -1.f,
        nullptr, 0LL, nullptr, 0, 2048, NN, NN, 2.f, 0);
    // ruT = sigmoid(gwT @ U^T) (K=512 slab path, unchanged)
    mfma2<float, 128, false, false, true><<<dim3(1, 32, BB), dim3(256), 0, stream>>>(
        gwT, 512, 0LL, Uall, NN, uB, 7, SLAB, 0, ruT, NN, (long long)128 * NN,
        (const float*)nullptr, 0.f, W(42), 0, nullptr, 128, NN, 512, 1.f, 2);
    // cand chain: rows 128..191 of each b-block, fused M=1024 (sh=6)
    k_u0cT<<<dim3((int)((n64 + 255) / 256)), dim3(256), 0, stream>>>(ruT, hgH, U0);
    mfma3<64, 128><<<dim3(16, 16, 1), dim3(256), 0, stream>>>(
        U0 + 128 * NN, NN, 0LL, 6, uB, Lh, NN, 0LL, U1 + 128 * NN, NN, 0LL, 6, uB,
        (const fp16*)nullptr, 0LL, 0.f, nullptr, 0LL, nullptr, 0, 1024, NN, NN, 1.f, 0);
    mfma3<64, 128><<<dim3(16, 16, 1), dim3(256), 0, stream>>>(
        U1 + 128 * NN, NN, 0LL, 6, uB, Lh, NN, 0LL, U2 + 128 * NN, NN, 0LL, 6, uB,
        (const fp16*)(U0 + 128 * NN), 0LL, -1.f, nullptr, 0LL, nullptr, 0, 1024, NN, NN,
        2.f, 0);
    mfma3<64, 128><<<dim3(16, 16, 1), dim3(256), 0, stream>>>(
        U2 + 128 * NN, NN, 0LL, 6, uB, Lh, NN, 0LL, U3 + 128 * NN, NN, 0LL, 6, uB,
        (const fp16*)(U1 + 128 * NN), 0LL, -1.f, nullptr, 0LL, nullptr, 0, 1024, NN, NN,
        2.f, 0);
    // cndT = tanh(cwT @ U^T)
    mfma2<float, 64, false, false, true><<<dim3(1, 32, BB), dim3(256), 0, stream>>>(
        cwT, 512, 0LL, Uall, NN, uB, 7, SLAB, 64, cndT, NN, (long long)64 * NN,
        (const float*)nullptr, 0.f, W(44), 0, nullptr, 64, NN, 512, 1.f, 3);
    k_h_updT<<<dim3((int)((n64 + 255) / 256)), dim3(256), 0, stream>>>(hgH, ruT, cndT);
  }

  // ---- output head ----
  k_trT<<<dim3((int)(((long long)BB * NN * 64 + 255) / 256)), dim3(256), 0, stream>>>(hgH,
                                                                                      htmp);
  launch_gemm(stream, (const float*)htmp, 64, 0LL, W(35), 64, 0LL, (float*)cndT, 64, 0LL,
              (float*)nullptr, 0LL, W(36), BB * NN, 64, 64, 1.f, 0.f, 1, 1);
  launch_gemm(stream, (const float*)cndT, 64, 0LL, W(37), 12, 0LL, (float*)ruT, 12, 0LL,
              (float*)nullptr, 0LL, W(38), BB * NN, 12, 64, 1.f, 0.f, 0, 1);
  k_out<<<dim3((BB * QQ * NN + 255) / 256), dim3(256), 0, stream>>>((const float*)ruT,
                                                                    (float*)d_out);
}

// Round 8
// 4677.601 us; speedup vs baseline: 1.9971x; 1.9971x over previous
//
#include <hip/hip_runtime.h>
#include <hip/hip_bf16.h>
#include <math.h>

typedef _Float16 fp16;
typedef _Float16 f16x8 __attribute__((ext_vector_type(8)));
typedef float f32x4 __attribute__((ext_vector_type(4)));

#define BB 16
#define PP 12
#define QQ 12
#define NN 2000
#define CC 1024

static __device__ __forceinline__ float ldf(float v) { return v; }
static __device__ __forceinline__ float ldf(fp16 v) { return (float)v; }
static __device__ __forceinline__ void stf(float* p, float v) { *p = v; }
static __device__ __forceinline__ void stf(fp16* p, float v) { *p = (fp16)v; }

// ---------- conversions / repacks ----------
__global__ void k_f2h(fp16* __restrict__ dst, const float* __restrict__ src, long long n) {
  long long i = (long long)blockIdx.x * 256 + threadIdx.x;
  if (i < n) dst[i] = (fp16)src[i];
}

// dcgru weights (512,O): row=f*4+t -> Wt[d][t*128+c] = src[(c*4+t)*O+d]
__global__ void k_gru_repackT(fp16* __restrict__ dst, const float* __restrict__ src, int O) {
  int i = blockIdx.x * 256 + threadIdx.x;
  if (i >= O * 512) return;
  int d = i >> 9;
  int kc = i & 511;
  int t = kc >> 7;
  int c = kc & 127;
  dst[i] = (fp16)src[(c * 4 + t) * O + d];
}

// (64,64) -> T[d][k] fp16
__global__ void k_w2T(fp16* __restrict__ dst, const float* __restrict__ src) {
  int i = blockIdx.x * 256 + threadIdx.x;
  if (i >= 4096) return;
  int d = i >> 6, k = i & 63;
  dst[i] = (fp16)src[k * 64 + d];
}

// ---------- laplacian ----------
__global__ void k_dinv(const float* __restrict__ adj, float* __restrict__ dinv) {
  int row = blockIdx.x;
  float s = 0.f;
  for (int j = threadIdx.x; j < NN; j += 256)
    s += fmaxf(adj[(long long)row * NN + j], adj[(long long)j * NN + row]);
  __shared__ float red[256];
  red[threadIdx.x] = s;
  __syncthreads();
  for (int st = 128; st > 0; st >>= 1) {
    if (threadIdx.x < st) red[threadIdx.x] += red[threadIdx.x + st];
    __syncthreads();
  }
  if (threadIdx.x == 0) {
    float d = red[0];
    dinv[row] = d > 0.f ? 1.0f / sqrtf(d) : 0.f;
  }
}

__global__ void k_L(const float* __restrict__ adj, const float* __restrict__ dinv,
                    fp16* __restrict__ Lh) {
  long long i = (long long)blockIdx.x * 256 + threadIdx.x;
  if (i >= (long long)NN * NN) return;
  int r = (int)(i / NN), c = (int)(i % NN);
  float a = fmaxf(adj[(long long)r * NN + c], adj[(long long)c * NN + r]);
  Lh[i] = (fp16)(-dinv[r] * a * dinv[c]);
}

__global__ void k_subdiag(fp16* __restrict__ M2) {
  int i = blockIdx.x * 256 + threadIdx.x;
  if (i >= NN) return;
  M2[(long long)i * NN + i] = (fp16)((float)M2[(long long)i * NN + i] - 1.0f);
}

// ---------- gumbel softmax -> fp16 ----------
__global__ void k_gumbel_softmax(const float* __restrict__ ml, const float* __restrict__ gn,
                                 fp16* __restrict__ mZ) {
  int row = blockIdx.x;
  __shared__ float buf[CC];
  __shared__ float red[256];
  int t = threadIdx.x;
  float mx = -1e30f;
  for (int j = t; j < CC; j += 256) {
    float u = gn[(long long)row * CC + j];
    float g = -logf(-logf(u + 1e-20f) + 1e-20f);
    float v = ml[(long long)row * CC + j] + g;
    buf[j] = v;
    mx = fmaxf(mx, v);
  }
  red[t] = mx;
  __syncthreads();
  for (int st = 128; st > 0; st >>= 1) {
    if (t < st) red[t] = fmaxf(red[t], red[t + st]);
    __syncthreads();
  }
  mx = red[0];
  __syncthreads();
  float s = 0.f;
  for (int j = t; j < CC; j += 256) {
    float e = expf(buf[j] - mx);
    buf[j] = e;
    s += e;
  }
  red[t] = s;
  __syncthreads();
  for (int st = 128; st > 0; st >>= 1) {
    if (t < st) red[t] += red[t + st];
    __syncthreads();
  }
  float inv = 1.0f / red[0];
  for (int j = t; j < CC; j += 256) mZ[(long long)row * CC + j] = (fp16)(buf[j] * inv);
}

__global__ void k_te(const int* __restrict__ TE, const float* __restrict__ w1,
                     const float* __restrict__ b1, float* __restrict__ tmp) {
  int i = blockIdx.x * 256 + threadIdx.x;
  if (i >= BB * PP * 64) return;
  int j = i & 63;
  int bp = i >> 6;
  int b = bp / PP, p = bp % PP;
  int te0 = TE[(b * (PP + QQ) + p) * 2 + 0];
  int te1 = TE[(b * (PP + QQ) + p) * 2 + 1];
  float v = w1[te0 * 64 + j] + w1[(7 + te1) * 64 + j] + b1[j];
  tmp[i] = fmaxf(v, 0.f);
}

__global__ void k_addb(float* __restrict__ dst, const float* __restrict__ b, int n) {
  int i = blockIdx.x * 256 + threadIdx.x;
  if (i < n) dst[i] += b[i & 63];
}

__global__ void k_zf1(const float* __restrict__ Z, const float* __restrict__ w1,
                      const float* __restrict__ b1, fp16* __restrict__ tmp) {
  long long i = (long long)blockIdx.x * 256 + threadIdx.x;
  if (i >= (long long)BB * PP * CC * 64) return;
  int j = (int)(i & 63);
  long long row = i >> 6;
  float v = Z[row * 2 + 0] * w1[j] + Z[row * 2 + 1] * w1[64 + j] + b1[j];
  tmp[i] = (fp16)fmaxf(v, 0.f);
}

__global__ void k_add_stez(fp16* __restrict__ Zf, const float* __restrict__ seZ,
                           const float* __restrict__ teZ) {
  long long i = (long long)blockIdx.x * 256 + threadIdx.x;
  if (i >= (long long)BB * PP * CC * 64) return;
  int j = (int)(i & 63);
  long long row = i >> 6;
  int c = (int)(row % CC);
  int bp = (int)(row / CC);
  Zf[i] = (fp16)((float)Zf[i] + seZ[c * 64 + j] + teZ[bp * 64 + j]);
}

// ---------- generic fp32-path GEMM (small ops) ----------
template <typename TA, typename TB, typename TC>
__global__ __launch_bounds__(256) void gemm_t(
    const TA* __restrict__ A, int lda, long long sA,
    const TB* __restrict__ Bm, int ldb, long long sB,
    TC* Cm, int ldc, long long sC,
    const TC* S, long long sS,
    const float* __restrict__ bias,
    int M, int Ncols, int K, float alpha, float beta, int act) {
  int bz = blockIdx.z;
  A += (long long)bz * sA;
  Bm += (long long)bz * sB;
  Cm += (long long)bz * sC;
  if (S) S += (long long)bz * sS;
  const int row0 = blockIdx.x * 64, col0 = blockIdx.y * 64;
  __shared__ float As[16][68];
  __shared__ float Bs[16][68];
  int tid = threadIdx.x, tx = tid & 15, ty = tid >> 4;
  float acc[4][4] = {};
  for (int k0 = 0; k0 < K; k0 += 16) {
#pragma unroll
    for (int j = 0; j < 4; ++j) {
      int e = tid + 256 * j;
      int m = e >> 4, kk = e & 15;
      int gm = row0 + m;
      As[kk][m] = (gm < M) ? ldf(A[(long long)gm * lda + k0 + kk]) : 0.f;
    }
#pragma unroll
    for (int j = 0; j < 4; ++j) {
      int e = tid + 256 * j;
      int kk = e >> 6, n = e & 63;
      int gn = col0 + n;
      Bs[kk][n] = (gn < Ncols) ? ldf(Bm[(long long)(k0 + kk) * ldb + gn]) : 0.f;
    }
    __syncthreads();
#pragma unroll
    for (int kk = 0; kk < 16; ++kk) {
      float a[4], bb[4];
#pragma unroll
      for (int i = 0; i < 4; ++i) a[i] = As[kk][ty * 4 + i];
#pragma unroll
      for (int j = 0; j < 4; ++j) bb[j] = Bs[kk][tx * 4 + j];
#pragma unroll
      for (int i = 0; i < 4; ++i)
#pragma unroll
        for (int j = 0; j < 4; ++j) acc[i][j] = fmaf(a[i], bb[j], acc[i][j]);
    }
    __syncthreads();
  }
#pragma unroll
  for (int i = 0; i < 4; ++i) {
    int r = row0 + ty * 4 + i;
    if (r >= M) continue;
#pragma unroll
    for (int j = 0; j < 4; ++j) {
      int cn = col0 + tx * 4 + j;
      if (cn >= Ncols) continue;
      float v = alpha * acc[i][j];
      if (bias) v += bias[cn];
      if (S) v += beta * ldf(S[(long long)r * ldc + cn]);
      if (act == 1) v = fmaxf(v, 0.f);
      else if (act == 2) v = 1.f / (1.f + expf(-v));
      else if (act == 3) v = tanhf(v);
      stf(&Cm[(long long)r * ldc + cn], v);
    }
  }
}

// ---------- mfma2: weight GEMMs (B in [k][n] layout via slab/cmap) ----------
template <typename TC, int MT, bool BIASROW>
__global__ __launch_bounds__(256) void mfma2(
    const fp16* __restrict__ A, int lda,
    const fp16* __restrict__ B, int ldb, long long bBatch, int bShift, long long bSlab,
    int bHi,
    TC* __restrict__ C, int ldc, long long cBatch,
    const float* __restrict__ bias,
    int M, int Ncols, int K, float alpha, int act) {
  __shared__ fp16 As[MT][40];
  __shared__ fp16 Bs[64][40];
  const int z = blockIdx.z;
  const int gm0 = blockIdx.x * MT, n0 = blockIdx.y * 64;
  B += (long long)z * bBatch;
  C += (long long)z * cBatch;
  const int tid = threadIdx.x;
  const int lane = tid & 63, wv = tid >> 6;
  const int wr = wv >> 1, wc = wv & 1;
  const int quad = lane >> 4, ln = lane & 15;
  const unsigned bMask = (1u << bShift) - 1u;
  constexpr int WM = MT / 32;
  f32x4 acc[WM][2];
#pragma unroll
  for (int i = 0; i < WM; ++i)
#pragma unroll
    for (int j = 0; j < 2; ++j) acc[i][j] = (f32x4){0.f, 0.f, 0.f, 0.f};

  for (int k0 = 0; k0 < K; k0 += 32) {
#pragma unroll
    for (int i = 0; i < MT / 64; ++i) {
      int c = tid + 256 * i;
      int row = c >> 2, seg = c & 3;
      int gm = gm0 + row;
      int kk0 = k0 + seg * 8;
      const fp16* src = A + (long long)gm * lda + kk0;
      if (gm < M && kk0 + 8 <= K) {
        *(f16x8*)&As[row][seg * 8] = *(const f16x8*)src;
      } else {
#pragma unroll
        for (int j = 0; j < 8; ++j)
          As[row][seg * 8 + j] = (gm < M && kk0 + j < K) ? src[j] : (fp16)0.f;
      }
    }
    {
      int kk = k0 + (tid & 31);
      int ngrp = tid >> 5;
      int slab = (int)((unsigned)kk >> bShift);
      int kin = (int)((unsigned)kk & bMask);
      int col = kin + (kin >= 64 ? bHi : 0);
      int n = n0 + ngrp * 8;
      const fp16* src = B + (long long)slab * bSlab + (long long)col * ldb + n;
      if (kk < K && n + 8 <= Ncols) {
        f16x8 v = *(const f16x8*)src;
#pragma unroll
        for (int j = 0; j < 8; ++j) Bs[ngrp * 8 + j][tid & 31] = v[j];
      } else {
#pragma unroll
        for (int j = 0; j < 8; ++j)
          Bs[ngrp * 8 + j][tid & 31] = (kk < K && n + j < Ncols) ? src[j] : (fp16)0.f;
      }
    }
    __syncthreads();
    f16x8 af[WM], bf[2];
#pragma unroll
    for (int wm = 0; wm < WM; ++wm)
      af[wm] = *(const f16x8*)&As[wr * (MT / 2) + wm * 16 + ln][quad * 8];
#pragma unroll
    for (int wn = 0; wn < 2; ++wn)
      bf[wn] = *(const f16x8*)&Bs[wc * 32 + wn * 16 + ln][quad * 8];
#pragma unroll
    for (int wm = 0; wm < WM; ++wm)
#pragma unroll
      for (int wn = 0; wn < 2; ++wn)
        acc[wm][wn] =
            __builtin_amdgcn_mfma_f32_16x16x32_f16(af[wm], bf[wn], acc[wm][wn], 0, 0, 0);
    __syncthreads();
  }
#pragma unroll
  for (int wm = 0; wm < WM; ++wm) {
#pragma unroll
    for (int wn = 0; wn < 2; ++wn) {
#pragma unroll
      for (int r = 0; r < 4; ++r) {
        int gm = gm0 + wr * (MT / 2) + wm * 16 + quad * 4 + r;
        int gn = n0 + wc * 32 + wn * 16 + ln;
        if (gm < M && gn < Ncols) {
          float v = alpha * acc[wm][wn][r];
          if (bias) v += BIASROW ? bias[gm] : bias[gn];
          if (act == 1) v = fmaxf(v, 0.f);
          else if (act == 2) v = 1.f / (1.f + expf(-v));
          else if (act == 3) v = tanhf(v);
          stf(&C[(long long)gm * ldc + gn], v);
        }
      }
    }
  }
}

// ---------- mfma3: all-b128 GEMM; M-split and N-split output mapping ----------
// C = act(alpha*A@B^T + rowBias + s2T + beta*S)  (B rows are [n][k], k-contig)
// A row  = A + zA*z + (gm>>aMsh)*aMslab + (gm&aMmask)*lda
// C/S idx= (gm>>cMsh)*cMslab + (gm&cMmask)*ldc + (gn>>cNsh)*cNslab + (gn&cNmask)
template <int MT, int NT>
__global__ __launch_bounds__(256) void mfma3(
    const fp16* __restrict__ A, int lda, long long zA, int aMsh, long long aMslab,
    const fp16* __restrict__ B, int ldb, long long zB,
    fp16* __restrict__ C, int ldc, long long zC, int cMsh, long long cMslab, int cNsh,
    long long cNslab,
    const fp16* __restrict__ S, long long zS, float beta,
    const float* __restrict__ rowBias, long long zRB,
    const float* __restrict__ s2T, int s2ld,
    int M, int Ncols, int K, float alpha, int act) {
  __shared__ fp16 As[MT][40];
  __shared__ fp16 Bs[NT][40];
  const int z = blockIdx.z;
  const int gm0 = blockIdx.x * MT, n0 = blockIdx.y * NT;
  A += (long long)z * zA;
  B += (long long)z * zB;
  C += (long long)z * zC;
  if (S) S += (long long)z * zS;
  const int tid = threadIdx.x;
  const int lane = tid & 63, wv = tid >> 6;
  const int wr = wv >> 1, wc = wv & 1;
  const int quad = lane >> 4, ln = lane & 15;
  const unsigned aMmask = (1u << aMsh) - 1u;
  const unsigned cMmask = (1u << cMsh) - 1u;
  const unsigned cNmask = (1u << cNsh) - 1u;
  constexpr int WM = MT / 32, WN = NT / 32;
  f32x4 acc[WM][WN];
#pragma unroll
  for (int i = 0; i < WM; ++i)
#pragma unroll
    for (int j = 0; j < WN; ++j) acc[i][j] = (f32x4){0.f, 0.f, 0.f, 0.f};

  for (int k0 = 0; k0 < K; k0 += 32) {
#pragma unroll
    for (int i = 0; i < MT / 64; ++i) {
      int c = tid + 256 * i;
      int row = c >> 2, seg = c & 3;
      int gm = gm0 + row;
      int kk0 = k0 + seg * 8;
      const fp16* src = A + ((long long)((unsigned)gm >> aMsh)) * aMslab +
                        (long long)(gm & aMmask) * lda + kk0;
      if (gm < M && kk0 + 8 <= K) {
        *(f16x8*)&As[row][seg * 8] = *(const f16x8*)src;
      } else {
#pragma unroll
        for (int j = 0; j < 8; ++j)
          As[row][seg * 8 + j] = (gm < M && kk0 + j < K) ? src[j] : (fp16)0.f;
      }
    }
#pragma unroll
    for (int i = 0; i < NT / 64; ++i) {
      int c = tid + 256 * i;
      int n = c >> 2, seg = c & 3;
      int gn = n0 + n;
      int kk0 = k0 + seg * 8;
      const fp16* src = B + (long long)gn * ldb + kk0;
      if (gn < Ncols && kk0 + 8 <= K) {
        *(f16x8*)&Bs[n][seg * 8] = *(const f16x8*)src;
      } else {
#pragma unroll
        for (int j = 0; j < 8; ++j)
          Bs[n][seg * 8 + j] = (gn < Ncols && kk0 + j < K) ? src[j] : (fp16)0.f;
      }
    }
    __syncthreads();
    f16x8 af[WM], bf[WN];
#pragma unroll
    for (int wm = 0; wm < WM; ++wm)
      af[wm] = *(const f16x8*)&As[wr * (MT / 2) + wm * 16 + ln][quad * 8];
#pragma unroll
    for (int wn = 0; wn < WN; ++wn)
      bf[wn] = *(const f16x8*)&Bs[wc * (NT / 2) + wn * 16 + ln][quad * 8];
#pragma unroll
    for (int wm = 0; wm < WM; ++wm)
#pragma unroll
      for (int wn = 0; wn < WN; ++wn)
        acc[wm][wn] =
            __builtin_amdgcn_mfma_f32_16x16x32_f16(af[wm], bf[wn], acc[wm][wn], 0, 0, 0);
    __syncthreads();
  }
#pragma unroll
  for (int wm = 0; wm < WM; ++wm) {
#pragma unroll
    for (int wn = 0; wn < WN; ++wn) {
#pragma unroll
      for (int r = 0; r < 4; ++r) {
        int gm = gm0 + wr * (MT / 2) + wm * 16 + quad * 4 + r;
        int gn = n0 + wc * (NT / 2) + wn * 16 + ln;
        if (gm < M && gn < Ncols) {
          float v = alpha * acc[wm][wn][r];
          if (rowBias) v += rowBias[(long long)z * zRB + gm];
          if (s2T) v += s2T[(long long)gn * s2ld + gm];
          long long ci = ((long long)((unsigned)gm >> cMsh)) * cMslab +
                         (long long)(gm & cMmask) * ldc +
                         ((long long)((unsigned)gn >> cNsh)) * cNslab + (gn & cNmask);
          if (S) v += beta * (float)S[ci];
          if (act == 1) v = fmaxf(v, 0.f);
          else if (act == 2) v = 1.f / (1.f + expf(-v));
          else if (act == 3) v = tanhf(v);
          C[ci] = (fp16)v;
        }
      }
    }
  }
}

// ---------- ConvLSTM conv as MFMA ----------
__global__ __launch_bounds__(256) void k_conv_mfma(
    const fp16* __restrict__ Zf, const fp16* __restrict__ h,
    const fp16* __restrict__ wcat, fp16* __restrict__ gates, int p) {
  __shared__ fp16 As[128][40];
  __shared__ fp16 Bs[64][40];
  const int gm0 = blockIdx.x * 128, n0 = blockIdx.y * 64;
  const int tid = threadIdx.x;
  const int lane = tid & 63, wv = tid >> 6;
  const int wr = wv >> 1, wc = wv & 1;
  const int quad = lane >> 4, ln = lane & 15;
  f32x4 acc[4][2];
#pragma unroll
  for (int i = 0; i < 4; ++i)
#pragma unroll
    for (int j = 0; j < 2; ++j) acc[i][j] = (f32x4){0.f, 0.f, 0.f, 0.f};

  for (int kb = 0; kb < 36; ++kb) {
    const int srcsel = kb >= 18;
    const int tap = (kb >> 1) % 9;
    const int half = kb & 1;
    const int dy = tap / 3 - 1, dx = tap % 3 - 1;
#pragma unroll
    for (int i = 0; i < 2; ++i) {
      int c = tid + 256 * i;
      int row = c >> 2, seg = c & 3;
      int m = gm0 + row;
      int b = m >> 10;
      int y = (m >> 5) & 31, x = m & 31;
      int yy = y + dy, xx = x + dx;
      bool valid = ((unsigned)yy < 32u) && ((unsigned)xx < 32u);
      f16x8 v;
      if (valid) {
        long long cell = ((long long)b << 10) + (yy << 5) + xx;
        const fp16* sp =
            srcsel ? (h + cell * 64)
                   : (Zf + ((((long long)(b * PP + p)) << 10) + (yy << 5) + xx) * 64);
        v = *(const f16x8*)(sp + half * 32 + seg * 8);
      } else {
#pragma unroll
        for (int j = 0; j < 8; ++j) v[j] = (fp16)0.f;
      }
      *(f16x8*)&As[row][seg * 8] = v;
    }
    {
      int kk = kb * 32 + (tid & 31);
      int ngrp = tid >> 5;
      int n = n0 + ngrp * 8;
      f16x8 v = *(const f16x8*)(wcat + (long long)kk * 256 + n);
#pragma unroll
      for (int j = 0; j < 8; ++j) Bs[ngrp * 8 + j][tid & 31] = v[j];
    }
    __syncthreads();
    f16x8 af[4], bf[2];
#pragma unroll
    for (int wm = 0; wm < 4; ++wm)
      af[wm] = *(const f16x8*)&As[wr * 64 + wm * 16 + ln][quad * 8];
#pragma unroll
    for (int wn = 0; wn < 2; ++wn)
      bf[wn] = *(const f16x8*)&Bs[wc * 32 + wn * 16 + ln][quad * 8];
#pragma unroll
    for (int wm = 0; wm < 4; ++wm)
#pragma unroll
      for (int wn = 0; wn < 2; ++wn)
        acc[wm][wn] =
            __builtin_amdgcn_mfma_f32_16x16x32_f16(af[wm], bf[wn], acc[wm][wn], 0, 0, 0);
    __syncthreads();
  }
#pragma unroll
  for (int wm = 0; wm < 4; ++wm)
#pragma unroll
    for (int wn = 0; wn < 2; ++wn)
#pragma unroll
      for (int r = 0; r < 4; ++r) {
        int gm = gm0 + wr * 64 + wm * 16 + quad * 4 + r;
        int gn = n0 + wc * 32 + wn * 16 + ln;
        gates[(long long)gm * 256 + gn] = (fp16)acc[wm][wn][r];
      }
}

__global__ void k_clstm_update(const fp16* __restrict__ gates, float* __restrict__ c,
                               fp16* __restrict__ h, fp16* __restrict__ ZclT, int p) {
  long long i = (long long)blockIdx.x * 256 + threadIdx.x;
  if (i >= (long long)BB * CC * 64) return;
  int d = (int)(i & 63);
  long long bc = i >> 6;
  int b = (int)(bc >> 10);
  int cell = (int)(bc & 1023);
  const fp16* g = gates + (((long long)b * CC) + cell) * 256;
  float gi = (float)g[d], gf = (float)g[64 + d], gg = (float)g[128 + d],
        go = (float)g[192 + d];
  float hs_f = fminf(fmaxf(0.2f * gf + 0.5f, 0.f), 1.f);
  float hs_i = fminf(fmaxf(0.2f * gi + 0.5f, 0.f), 1.f);
  float hs_o = fminf(fmaxf(0.2f * go + 0.5f, 0.f), 1.f);
  float cv = hs_f * c[i] + hs_i * tanhf(gg);
  c[i] = cv;
  float hv = hs_o * tanhf(cv);
  h[i] = (fp16)hv;
  ZclT[(((long long)(b * PP + p)) * 64 + d) * CC + cell] = (fp16)hv;
}

__global__ void k_tmat(const float* __restrict__ X, const float* __restrict__ w1,
                       const float* __restrict__ b1, fp16* __restrict__ T) {
  long long i = (long long)blockIdx.x * 256 + threadIdx.x;
  if (i >= (long long)BB * PP * NN * 64) return;
  int j = (int)(i & 63);
  long long row = i >> 6;
  T[i] = (fp16)fmaxf(X[row] * w1[j] + b1[j], 0.f);
}

// ---------- DCGRU elementwise ----------
// U0[b][192 rows][2048]: rows 0..63 x_p, 64..127 h, 128..191 rh
__global__ void k_u0T(const fp16* __restrict__ ZXt, const fp16* __restrict__ hgH,
                      fp16* __restrict__ U0, int p) {
  long long i = (long long)blockIdx.x * 256 + threadIdx.x;
  if (i >= (long long)BB * 128 * (NN / 8)) return;
  int n8 = (int)(i % (NN / 8));
  int c = (int)((i / (NN / 8)) & 127);
  int b = (int)(i / ((NN / 8) * 128));
  f16x8 v;
  if (c < 64)
    v = *(const f16x8*)(ZXt + ((((long long)(b * PP + p)) * 64 + c) * NN) + n8 * 8);
  else
    v = *(const f16x8*)(hgH + (long long)(c - 64) * (BB * NN) + b * NN + n8 * 8);
  *(f16x8*)(U0 + ((long long)b * 192 + c) * 2048 + n8 * 8) = v;
}

__global__ void k_u0cT(const fp16* __restrict__ ruT, const fp16* __restrict__ hgH,
                       fp16* __restrict__ U0) {
  long long i = (long long)blockIdx.x * 256 + threadIdx.x;
  if (i >= (long long)BB * 64 * NN) return;
  int n = (int)(i % NN);
  int d = (int)((i / NN) & 63);
  int b = (int)(i / (NN * 64));
  float r = (float)ruT[((long long)b * 128 + d) * NN + n];
  float h = (float)hgH[(long long)d * (BB * NN) + b * NN + n];
  U0[((long long)b * 192 + 128 + d) * 2048 + n] = (fp16)(r * h);
}

__global__ void k_h_updT(fp16* __restrict__ hgH, const fp16* __restrict__ ruT,
                         const fp16* __restrict__ cndT) {
  long long i = (long long)blockIdx.x * 256 + threadIdx.x;
  if (i >= (long long)BB * 64 * NN) return;
  int n = (int)(i % NN);
  int d = (int)((i / NN) & 63);
  int b = (int)(i / (NN * 64));
  float u = (float)ruT[((long long)b * 128 + 64 + d) * NN + n];
  long long hi = (long long)d * (BB * NN) + b * NN + n;
  float cn = (float)cndT[((long long)b * 64 + d) * NN + n];
  hgH[hi] = (fp16)(u * (float)hgH[hi] + (1.f - u) * cn);
}

__global__ void k_trT(const fp16* __restrict__ hgH, float* __restrict__ htmp) {
  long long i = (long long)blockIdx.x * 256 + threadIdx.x;
  if (i >= (long long)BB * NN * 64) return;
  int d = (int)(i & 63);
  long long bn = i >> 6;
  htmp[i] = (float)hgH[(long long)d * (BB * NN) + bn];
}

__global__ void k_out(const float* __restrict__ Y, float* __restrict__ out) {
  int i = blockIdx.x * 256 + threadIdx.x;
  if (i >= BB * QQ * NN) return;
  int n = i % NN;
  int bq = i / NN;
  int b = bq / QQ, q = bq % QQ;
  out[i] = Y[((long long)b * NN + n) * 12 + q];
}

// ---------- host helpers ----------
template <typename TA, typename TB, typename TC>
static void launch_gemm(hipStream_t stream, const TA* A, int lda, long long sA,
                        const TB* Bm, int ldb, long long sB, TC* Cm, int ldc, long long sC,
                        const TC* S, long long sS, const float* bias, int M, int Nc, int K,
                        float alpha, float beta, int act, int batch) {
  dim3 g((M + 63) / 64, (Nc + 63) / 64, batch);
  gemm_t<TA, TB, TC><<<g, dim3(256), 0, stream>>>(A, lda, sA, Bm, ldb, sB, Cm, ldc, sC, S,
                                                  sS, bias, M, Nc, K, alpha, beta, act);
}

extern "C" void kernel_launch(void* const* d_in, const int* in_sizes, int n_in,
                              void* d_out, int out_size, void* d_ws, size_t ws_size,
                              hipStream_t stream) {
  char* base = (char*)d_ws;
  size_t off = 0;
  auto alloc_bytes = [&](size_t nb) -> char* {
    char* p = base + off;
    off += (nb + 255) & ~(size_t)255;
    return p;
  };
  auto allocf = [&](size_t n) -> float* { return (float*)alloc_bytes(n * 4); };
  auto alloch = [&](size_t n) -> fp16* { return (fp16*)alloc_bytes(n * 2); };

  const float* X = (const float*)d_in[0];
  const float* Z = (const float*)d_in[1];
  const int* TE = (const int*)d_in[2];
  const float* adj_gg = (const float*)d_in[3];
  const float* adj_gr = (const float*)d_in[4];
  const float* gumbel = (const float*)d_in[5];
  const float* se_x = (const float*)d_in[6];
  const float* se_z = (const float*)d_in[7];
  const float* movement = (const float*)d_in[8];
  auto W = [&](int i) { return (const float*)d_in[i]; };

  // ---- allocations ----
  fp16* wcat = alloch(1152 * 256);
  fp16* gwT = alloch(128 * 512);
  fp16* cwT = alloch(64 * 512);
  fp16* w2T = alloch(64 * 64);
  fp16* w2mT = alloch(64 * 64);
  float* dinv = allocf(NN);
  fp16* LMall = alloch((size_t)6144 * NN);  // rows: [L(2000) pad | M2 | M3], stride 2000
  fp16* mZh = alloch((size_t)CC * CC);
  fp16* agh2 = alloch((size_t)NN * CC);
  float* seZ = allocf(CC * 64);
  float* teZ = allocf(BB * PP * 64);
  float* seX = allocf(NN * 64);
  float* teXb = allocf(BB * PP * 64);
  float* mtmp = allocf(NN * 64);
  float* tetmp = allocf(BB * PP * 64);
  fp16* hgH = alloch((size_t)64 * BB * NN);   // [64 d][b*2000+n]
  fp16* ruT = alloch((size_t)BB * 128 * NN);  // [b][128][2000]
  fp16* cndT = alloch((size_t)BB * 64 * NN);  // [b][64][2000]
  // pool (50.33MB): U slabs 4x[16][192][2048] fp16; aliases conv gates/chh/ccc,
  // Zmix+ZmovT, Tmat, htmp
  char* pool = alloc_bytes(50331648);
  fp16* Uall = (fp16*)pool;
  fp16* gates = (fp16*)pool;
  fp16* chh = (fp16*)(pool + 8388608);
  float* ccc = (float*)(pool + 12582912);
  fp16* Zmix = (fp16*)pool;
  fp16* ZmovT = (fp16*)(pool + 25165824);
  fp16* Tmat = (fp16*)pool;
  float* htmp = (float*)pool;
  // zpool: Zf [bp][1024][64] then ZXt [bp][64][2000]
  fp16* zpool = alloch((size_t)BB * PP * NN * 64);
  fp16* Zf = zpool;
  fp16* ZXt = zpool;
  fp16* Zc = alloch((size_t)BB * PP * CC * 64);  // zf1 scratch, then ZclT

  if (off > ws_size) return;  // soft-fail diagnostic

  const long long uB = 192LL * 2048;  // per-b stride in a U slab
  const long long USL = 16LL * uB;    // slab stride
  fp16* Lh = LMall;
  fp16* M2h = LMall + 2048LL * NN;
  fp16* M3h = LMall + 4096LL * NN;

  // ---- precompute ----
  k_f2h<<<dim3(576), dim3(256), 0, stream>>>(wcat, W(39), 576 * 256);
  k_f2h<<<dim3(576), dim3(256), 0, stream>>>(wcat + 576 * 256, W(40), 576 * 256);
  k_gru_repackT<<<dim3(256), dim3(256), 0, stream>>>(gwT, W(41), 128);
  k_gru_repackT<<<dim3(128), dim3(256), 0, stream>>>(cwT, W(43), 64);
  k_w2T<<<dim3(16), dim3(256), 0, stream>>>(w2T, W(31));
  k_w2T<<<dim3(16), dim3(256), 0, stream>>>(w2mT, W(33));
  k_dinv<<<dim3(NN), dim3(256), 0, stream>>>(adj_gg, dinv);
  hipMemsetAsync(LMall, 0, (size_t)6144 * NN * 2, stream);
  k_L<<<dim3((NN * NN + 255) / 256), dim3(256), 0, stream>>>(adj_gg, dinv, Lh);
  // M2 = 2*L@L - I ; M3 = 2*L@M2 - L  (L,M2 symmetric -> A@B^T form valid)
  mfma3<128, 128><<<dim3(16, 16, 1), dim3(256), 0, stream>>>(
      Lh, NN, 0LL, 31, 0LL, Lh, NN, 0LL, M2h, NN, 0LL, 31, 0LL, 31, 0LL,
      (const fp16*)nullptr, 0LL, 0.f, nullptr, 0LL, nullptr, 0, NN, NN, NN, 2.f, 0);
  k_subdiag<<<dim3((NN + 255) / 256), dim3(256), 0, stream>>>(M2h);
  mfma3<128, 128><<<dim3(16, 16, 1), dim3(256), 0, stream>>>(
      Lh, NN, 0LL, 31, 0LL, M2h, NN, 0LL, M3h, NN, 0LL, 31, 0LL, 31, 0LL,
      (const fp16*)Lh, 0LL, -1.f, nullptr, 0LL, nullptr, 0, NN, NN, NN, 2.f, 0);
  k_gumbel_softmax<<<dim3(CC), dim3(256), 0, stream>>>(movement, gumbel, mZh);
  k_f2h<<<dim3((NN * CC + 255) / 256), dim3(256), 0, stream>>>(agh2, adj_gr,
                                                               (long long)NN * CC);

  // ---- STEZ / STEX ----
  launch_gemm(stream, se_z, 64, 0LL, W(17), 64, 0LL, mtmp, 64, 0LL, (float*)nullptr, 0LL,
              W(18), CC, 64, 64, 1.f, 0.f, 1, 1);
  launch_gemm(stream, (const float*)mtmp, 64, 0LL, W(19), 64, 0LL, seZ, 64, 0LL,
              (float*)nullptr, 0LL, W(20), CC, 64, 64, 1.f, 0.f, 0, 1);
  k_te<<<dim3((BB * PP * 64 + 255) / 256), dim3(256), 0, stream>>>(TE, W(21), W(22), tetmp);
  launch_gemm(stream, (const float*)tetmp, 64, 0LL, W(23), 64, 0LL, teZ, 64, 0LL,
              (float*)nullptr, 0LL, W(24), BB * PP, 64, 64, 1.f, 0.f, 0, 1);
  launch_gemm(stream, se_x, 64, 0LL, W(9), 64, 0LL, mtmp, 64, 0LL, (float*)nullptr, 0LL,
              W(10), NN, 64, 64, 1.f, 0.f, 1, 1);
  launch_gemm(stream, (const float*)mtmp, 64, 0LL, W(11), 64, 0LL, seX, 64, 0LL,
              (float*)nullptr, 0LL, W(12), NN, 64, 64, 1.f, 0.f, 0, 1);
  k_te<<<dim3((BB * PP * 64 + 255) / 256), dim3(256), 0, stream>>>(TE, W(13), W(14), tetmp);
  launch_gemm(stream, (const float*)tetmp, 64, 0LL, W(15), 64, 0LL, teXb, 64, 0LL,
              (float*)nullptr, 0LL, W(16), BB * PP, 64, 64, 1.f, 0.f, 0, 1);
  k_addb<<<dim3((BB * PP * 64 + 255) / 256), dim3(256), 0, stream>>>(teXb, W(32),
                                                                     BB * PP * 64);

  // ---- Zf = mlp2(Z) + STEZ ----
  long long nZ = (long long)BB * PP * CC * 64;
  k_zf1<<<dim3((int)((nZ + 255) / 256)), dim3(256), 0, stream>>>(Z, W(25), W(26), Zc);
  launch_gemm(stream, (const fp16*)Zc, 64, 0LL, W(27), 64, 0LL, Zf, 64, 0LL,
              (fp16*)nullptr, 0LL, W(28), BB * PP * CC, 64, 64, 1.f, 0.f, 0, 1);
  k_add_stez<<<dim3((int)((nZ + 255) / 256)), dim3(256), 0, stream>>>(Zf, seZ, teZ);

  // ---- ConvLSTM (writes ZclT into Zc) ----
  hipMemsetAsync(chh, 0, (size_t)BB * CC * 64 * 2, stream);
  hipMemsetAsync(ccc, 0, (size_t)BB * CC * 64 * 4, stream);
  for (int p = 0; p < PP; ++p) {
    k_conv_mfma<<<dim3(BB * CC / 128, 4), dim3(256), 0, stream>>>(Zf, chh, wcat, gates, p);
    k_clstm_update<<<dim3((int)(((long long)BB * CC * 64 + 255) / 256)), dim3(256), 0,
                     stream>>>(gates, ccc, chh, Zc, p);
  }

  // ---- movement chain (all-b128) ----
  mfma3<128, 64><<<dim3(8, 1, 192), dim3(256), 0, stream>>>(
      mZh, CC, 0LL, 31, 0LL, (const fp16*)Zc, CC, (long long)64 * CC, Zmix, 64,
      (long long)CC * 64, 31, 0LL, 31, 0LL, (const fp16*)nullptr, 0LL, 0.f, nullptr, 0LL,
      nullptr, 0, CC, 64, CC, 1.f, 0);
  mfma3<64, 128><<<dim3(1, 8, 192), dim3(256), 0, stream>>>(
      w2mT, 64, 0LL, 31, 0LL, Zmix, 64, (long long)CC * 64, ZmovT, CC, (long long)64 * CC,
      31, 0LL, 31, 0LL, (const fp16*)nullptr, 0LL, 0.f, W(34), 0LL, nullptr, 0, 64, CC, 64,
      1.f, 1);
  mfma3<64, 128><<<dim3(1, 16, 192), dim3(256), 0, stream>>>(
      ZmovT, CC, (long long)64 * CC, 31, 0LL, agh2, CC, 0LL, ZXt, NN, (long long)64 * NN,
      31, 0LL, 31, 0LL, (const fp16*)nullptr, 0LL, 0.f, teXb, 64LL, seX, 64, 64, NN, CC,
      1.f, 0);

  // ---- ZXt += (relu(X*w1+b1) @ w2)^T ----
  k_tmat<<<dim3((int)(((long long)BB * PP * NN * 64 + 255) / 256)), dim3(256), 0, stream>>>(
      X, W(29), W(30), Tmat);
  mfma3<64, 128><<<dim3(1, 16, 192), dim3(256), 0, stream>>>(
      w2T, 64, 0LL, 31, 0LL, Tmat, 64, (long long)NN * 64, ZXt, NN, (long long)64 * NN, 31,
      0LL, 31, 0LL, (const fp16*)ZXt, (long long)64 * NN, 1.f, nullptr, 0LL, nullptr, 0,
      64, NN, 64, 1.f, 0);

  // ---- DCGRU ----
  hipMemsetAsync(hgH, 0, (size_t)64 * BB * NN * 2, stream);
  fp16* U0 = Uall;
  fp16* U1 = Uall + USL;
  const long long nU0 = (long long)BB * 128 * (NN / 8);
  const long long n64 = (long long)BB * 64 * NN;
  for (int p = 0; p < PP; ++p) {
    // U0 rows 0..127 = [x_p | h]
    k_u0T<<<dim3((int)((nU0 + 255) / 256)), dim3(256), 0, stream>>>(ZXt, hgH, U0, p);
    // gate+h chain: [T1|T2|T3](rows 0..127) = U0[x|h] @ [L|M2|M3] -> U1..U3
    mfma3<128, 128><<<dim3(16, 48, 1), dim3(256), 0, stream>>>(
        U0, 2048, 0LL, 7, uB, LMall, NN, 0LL, U1, 2048, 0LL, 7, uB, 11, USL,
        (const fp16*)nullptr, 0LL, 0.f, nullptr, 0LL, nullptr, 0, 2048, 6144, NN, 1.f, 0);
    // ruT = sigmoid(gwT @ [T0..T3, cols 0..127])
    mfma2<fp16, 128, true><<<dim3(1, 32, BB), dim3(256), 0, stream>>>(
        gwT, 512, Uall, 2048, uB, 7, USL, 0, ruT, NN, (long long)128 * NN, W(42), 128, NN,
        512, 1.f, 2);
    // U0 rows 128..191 = r*h
    k_u0cT<<<dim3((int)((n64 + 255) / 256)), dim3(256), 0, stream>>>(ruT, hgH, U0);
    // cand rh chain -> U1..U3 rows 128..191
    mfma3<128, 64><<<dim3(8, 96, 1), dim3(256), 0, stream>>>(
        U0 + 128 * 2048, 2048, 0LL, 6, uB, LMall, NN, 0LL, U1 + 128 * 2048, 2048, 0LL, 6,
        uB, 11, USL, (const fp16*)nullptr, 0LL, 0.f, nullptr, 0LL, nullptr, 0, 1024, 6144,
        NN, 1.f, 0);
    // cndT = tanh(cwT @ [x|rh per term])  (bHi=64 maps k>=64 to rows 128..191)
    mfma2<fp16, 64, true><<<dim3(1, 32, BB), dim3(256), 0, stream>>>(
        cwT, 512, Uall, 2048, uB, 7, USL, 64, cndT, NN, (long long)64 * NN, W(44), 64, NN,
        512, 1.f, 3);
    k_h_updT<<<dim3((int)((n64 + 255) / 256)), dim3(256), 0, stream>>>(hgH, ruT, cndT);
  }

  // ---- output head ----
  k_trT<<<dim3((int)(((long long)BB * NN * 64 + 255) / 256)), dim3(256), 0, stream>>>(hgH,
                                                                                      htmp);
  launch_gemm(stream, (const float*)htmp, 64, 0LL, W(35), 64, 0LL, (float*)ruT, 64, 0LL,
              (float*)nullptr, 0LL, W(36), BB * NN, 64, 64, 1.f, 0.f, 1, 1);
  launch_gemm(stream, (const float*)ruT, 64, 0LL, W(37), 12, 0LL, (float*)cndT, 12, 0LL,
              (float*)nullptr, 0LL, W(38), BB * NN, 12, 64, 1.f, 0.f, 0, 1);
  k_out<<<dim3((BB * QQ * NN + 255) / 256), dim3(256), 0, stream>>>((const float*)cndT,
                                                                    (float*)d_out);
}

// Round 11
// 4618.558 us; speedup vs baseline: 2.0227x; 1.0128x over previous
//
#include <hip/hip_runtime.h>
#include <hip/hip_bf16.h>
#include <math.h>

typedef _Float16 fp16;
typedef _Float16 f16x8 __attribute__((ext_vector_type(8)));
typedef float f32x4 __attribute__((ext_vector_type(4)));

#define BB 16
#define PP 12
#define QQ 12
#define NN 2000
#define CC 1024

static __device__ __forceinline__ float ldf(float v) { return v; }
static __device__ __forceinline__ float ldf(fp16 v) { return (float)v; }
static __device__ __forceinline__ void stf(float* p, float v) { *p = v; }
static __device__ __forceinline__ void stf(fp16* p, float v) { *p = (fp16)v; }

// ---------- conversions / repacks ----------
__global__ void k_f2h(fp16* __restrict__ dst, const float* __restrict__ src, long long n) {
  long long i = (long long)blockIdx.x * 256 + threadIdx.x;
  if (i < n) dst[i] = (fp16)src[i];
}

// dcgru weights (512,O): row=f*4+t -> Wt[d][t*128+c] = src[(c*4+t)*O+d]
__global__ void k_gru_repackT(fp16* __restrict__ dst, const float* __restrict__ src, int O) {
  int i = blockIdx.x * 256 + threadIdx.x;
  if (i >= O * 512) return;
  int d = i >> 9;
  int kc = i & 511;
  int t = kc >> 7;
  int c = kc & 127;
  dst[i] = (fp16)src[(c * 4 + t) * O + d];
}

// (64,64) -> T[d][k] fp16
__global__ void k_w2T(fp16* __restrict__ dst, const float* __restrict__ src) {
  int i = blockIdx.x * 256 + threadIdx.x;
  if (i >= 4096) return;
  int d = i >> 6, k = i & 63;
  dst[i] = (fp16)src[k * 64 + d];
}

// ---------- laplacian ----------
__global__ void k_dinv(const float* __restrict__ adj, float* __restrict__ dinv) {
  int row = blockIdx.x;
  float s = 0.f;
  for (int j = threadIdx.x; j < NN; j += 256)
    s += fmaxf(adj[(long long)row * NN + j], adj[(long long)j * NN + row]);
  __shared__ float red[256];
  red[threadIdx.x] = s;
  __syncthreads();
  for (int st = 128; st > 0; st >>= 1) {
    if (threadIdx.x < st) red[threadIdx.x] += red[threadIdx.x + st];
    __syncthreads();
  }
  if (threadIdx.x == 0) {
    float d = red[0];
    dinv[row] = d > 0.f ? 1.0f / sqrtf(d) : 0.f;
  }
}

__global__ void k_L(const float* __restrict__ adj, const float* __restrict__ dinv,
                    fp16* __restrict__ Lh) {
  long long i = (long long)blockIdx.x * 256 + threadIdx.x;
  if (i >= (long long)NN * NN) return;
  int r = (int)(i / NN), c = (int)(i % NN);
  float a = fmaxf(adj[(long long)r * NN + c], adj[(long long)c * NN + r]);
  Lh[i] = (fp16)(-dinv[r] * a * dinv[c]);
}

__global__ void k_subdiag(fp16* __restrict__ M2) {
  int i = blockIdx.x * 256 + threadIdx.x;
  if (i >= NN) return;
  M2[(long long)i * NN + i] = (fp16)((float)M2[(long long)i * NN + i] - 1.0f);
}

// ---------- gumbel softmax -> fp16 ----------
__global__ void k_gumbel_softmax(const float* __restrict__ ml, const float* __restrict__ gn,
                                 fp16* __restrict__ mZ) {
  int row = blockIdx.x;
  __shared__ float buf[CC];
  __shared__ float red[256];
  int t = threadIdx.x;
  float mx = -1e30f;
  for (int j = t; j < CC; j += 256) {
    float u = gn[(long long)row * CC + j];
    float g = -logf(-logf(u + 1e-20f) + 1e-20f);
    float v = ml[(long long)row * CC + j] + g;
    buf[j] = v;
    mx = fmaxf(mx, v);
  }
  red[t] = mx;
  __syncthreads();
  for (int st = 128; st > 0; st >>= 1) {
    if (t < st) red[t] = fmaxf(red[t], red[t + st]);
    __syncthreads();
  }
  mx = red[0];
  __syncthreads();
  float s = 0.f;
  for (int j = t; j < CC; j += 256) {
    float e = expf(buf[j] - mx);
    buf[j] = e;
    s += e;
  }
  red[t] = s;
  __syncthreads();
  for (int st = 128; st > 0; st >>= 1) {
    if (t < st) red[t] += red[t + st];
    __syncthreads();
  }
  float inv = 1.0f / red[0];
  for (int j = t; j < CC; j += 256) mZ[(long long)row * CC + j] = (fp16)(buf[j] * inv);
}

__global__ void k_te(const int* __restrict__ TE, const float* __restrict__ w1,
                     const float* __restrict__ b1, float* __restrict__ tmp) {
  int i = blockIdx.x * 256 + threadIdx.x;
  if (i >= BB * PP * 64) return;
  int j = i & 63;
  int bp = i >> 6;
  int b = bp / PP, p = bp % PP;
  int te0 = TE[(b * (PP + QQ) + p) * 2 + 0];
  int te1 = TE[(b * (PP + QQ) + p) * 2 + 1];
  float v = w1[te0 * 64 + j] + w1[(7 + te1) * 64 + j] + b1[j];
  tmp[i] = fmaxf(v, 0.f);
}

__global__ void k_addb(float* __restrict__ dst, const float* __restrict__ b, int n) {
  int i = blockIdx.x * 256 + threadIdx.x;
  if (i < n) dst[i] += b[i & 63];
}

__global__ void k_zf1(const float* __restrict__ Z, const float* __restrict__ w1,
                      const float* __restrict__ b1, fp16* __restrict__ tmp) {
  long long i = (long long)blockIdx.x * 256 + threadIdx.x;
  if (i >= (long long)BB * PP * CC * 64) return;
  int j = (int)(i & 63);
  long long row = i >> 6;
  float v = Z[row * 2 + 0] * w1[j] + Z[row * 2 + 1] * w1[64 + j] + b1[j];
  tmp[i] = (fp16)fmaxf(v, 0.f);
}

__global__ void k_add_stez(fp16* __restrict__ Zf, const float* __restrict__ seZ,
                           const float* __restrict__ teZ) {
  long long i = (long long)blockIdx.x * 256 + threadIdx.x;
  if (i >= (long long)BB * PP * CC * 64) return;
  int j = (int)(i & 63);
  long long row = i >> 6;
  int c = (int)(row % CC);
  int bp = (int)(row / CC);
  Zf[i] = (fp16)((float)Zf[i] + seZ[c * 64 + j] + teZ[bp * 64 + j]);
}

// ---------- generic fp32-path GEMM (small ops) ----------
template <typename TA, typename TB, typename TC>
__global__ __launch_bounds__(256) void gemm_t(
    const TA* __restrict__ A, int lda, long long sA,
    const TB* __restrict__ Bm, int ldb, long long sB,
    TC* Cm, int ldc, long long sC,
    const TC* S, long long sS,
    const float* __restrict__ bias,
    int M, int Ncols, int K, float alpha, float beta, int act) {
  int bz = blockIdx.z;
  A += (long long)bz * sA;
  Bm += (long long)bz * sB;
  Cm += (long long)bz * sC;
  if (S) S += (long long)bz * sS;
  const int row0 = blockIdx.x * 64, col0 = blockIdx.y * 64;
  __shared__ float As[16][68];
  __shared__ float Bs[16][68];
  int tid = threadIdx.x, tx = tid & 15, ty = tid >> 4;
  float acc[4][4] = {};
  for (int k0 = 0; k0 < K; k0 += 16) {
#pragma unroll
    for (int j = 0; j < 4; ++j) {
      int e = tid + 256 * j;
      int m = e >> 4, kk = e & 15;
      int gm = row0 + m;
      As[kk][m] = (gm < M) ? ldf(A[(long long)gm * lda + k0 + kk]) : 0.f;
    }
#pragma unroll
    for (int j = 0; j < 4; ++j) {
      int e = tid + 256 * j;
      int kk = e >> 6, n = e & 63;
      int gn = col0 + n;
      Bs[kk][n] = (gn < Ncols) ? ldf(Bm[(long long)(k0 + kk) * ldb + gn]) : 0.f;
    }
    __syncthreads();
#pragma unroll
    for (int kk = 0; kk < 16; ++kk) {
      float a[4], bb[4];
#pragma unroll
      for (int i = 0; i < 4; ++i) a[i] = As[kk][ty * 4 + i];
#pragma unroll
      for (int j = 0; j < 4; ++j) bb[j] = Bs[kk][tx * 4 + j];
#pragma unroll
      for (int i = 0; i < 4; ++i)
#pragma unroll
        for (int j = 0; j < 4; ++j) acc[i][j] = fmaf(a[i], bb[j], acc[i][j]);
    }
    __syncthreads();
  }
#pragma unroll
  for (int i = 0; i < 4; ++i) {
    int r = row0 + ty * 4 + i;
    if (r >= M) continue;
#pragma unroll
    for (int j = 0; j < 4; ++j) {
      int cn = col0 + tx * 4 + j;
      if (cn >= Ncols) continue;
      float v = alpha * acc[i][j];
      if (bias) v += bias[cn];
      if (S) v += beta * ldf(S[(long long)r * ldc + cn]);
      if (act == 1) v = fmaxf(v, 0.f);
      else if (act == 2) v = 1.f / (1.f + expf(-v));
      else if (act == 3) v = tanhf(v);
      stf(&Cm[(long long)r * ldc + cn], v);
    }
  }
}

// ---------- mfma2: DCGRU weight GEMMs with fused GRU epilogues ----------
// MODE 1 (ru):  C=ruT [z][128][NN]; sigmoid; rows<64 also write rh=r*h into rhOut
// MODE 2 (cnd): tanh; h' = u*h + (1-u)*v written in-place into C (=U0 h-rows)
template <int MT, int MODE>
__global__ __launch_bounds__(256) void mfma2(
    const fp16* __restrict__ A, int lda,
    const fp16* __restrict__ B, int ldb, long long bBatch, int bShift, long long bSlab,
    int bHi,
    fp16* __restrict__ C, int ldc, long long cBatch,
    const float* __restrict__ bias,
    fp16* __restrict__ rhOut, const fp16* __restrict__ hIn, long long xStride,
    const fp16* __restrict__ uIn, long long uStride,
    int M, int Ncols, int K, float alpha) {
  __shared__ fp16 As[MT][40];
  __shared__ fp16 Bs[64][40];
  const int z = blockIdx.z;
  const int gm0 = blockIdx.x * MT, n0 = blockIdx.y * 64;
  B += (long long)z * bBatch;
  C += (long long)z * cBatch;
  if (rhOut) rhOut += (long long)z * xStride;
  if (hIn) hIn += (long long)z * xStride;
  if (uIn) uIn += (long long)z * uStride;
  const int tid = threadIdx.x;
  const int lane = tid & 63, wv = tid >> 6;
  const int wr = wv >> 1, wc = wv & 1;
  const int quad = lane >> 4, ln = lane & 15;
  const unsigned bMask = (1u << bShift) - 1u;
  constexpr int WM = MT / 32;
  f32x4 acc[WM][2];
#pragma unroll
  for (int i = 0; i < WM; ++i)
#pragma unroll
    for (int j = 0; j < 2; ++j) acc[i][j] = (f32x4){0.f, 0.f, 0.f, 0.f};

  for (int k0 = 0; k0 < K; k0 += 32) {
#pragma unroll
    for (int i = 0; i < MT / 64; ++i) {
      int c = tid + 256 * i;
      int row = c >> 2, seg = c & 3;
      int gm = gm0 + row;
      int kk0 = k0 + seg * 8;
      const fp16* src = A + (long long)gm * lda + kk0;
      if (gm < M && kk0 + 8 <= K) {
        *(f16x8*)&As[row][seg * 8] = *(const f16x8*)src;
      } else {
#pragma unroll
        for (int j = 0; j < 8; ++j)
          As[row][seg * 8 + j] = (gm < M && kk0 + j < K) ? src[j] : (fp16)0.f;
      }
    }
    {
      int kk = k0 + (tid & 31);
      int ngrp = tid >> 5;
      int slab = (int)((unsigned)kk >> bShift);
      int kin = (int)((unsigned)kk & bMask);
      int col = kin + (kin >= 64 ? bHi : 0);
      int n = n0 + ngrp * 8;
      const fp16* src = B + (long long)slab * bSlab + (long long)col * ldb + n;
      if (kk < K && n + 8 <= Ncols) {
        f16x8 v = *(const f16x8*)src;
#pragma unroll
        for (int j = 0; j < 8; ++j) Bs[ngrp * 8 + j][tid & 31] = v[j];
      } else {
#pragma unroll
        for (int j = 0; j < 8; ++j)
          Bs[ngrp * 8 + j][tid & 31] = (kk < K && n + j < Ncols) ? src[j] : (fp16)0.f;
      }
    }
    __syncthreads();
    f16x8 af[WM], bf[2];
#pragma unroll
    for (int wm = 0; wm < WM; ++wm)
      af[wm] = *(const f16x8*)&As[wr * (MT / 2) + wm * 16 + ln][quad * 8];
#pragma unroll
    for (int wn = 0; wn < 2; ++wn)
      bf[wn] = *(const f16x8*)&Bs[wc * 32 + wn * 16 + ln][quad * 8];
#pragma unroll
    for (int wm = 0; wm < WM; ++wm)
#pragma unroll
      for (int wn = 0; wn < 2; ++wn)
        acc[wm][wn] =
            __builtin_amdgcn_mfma_f32_16x16x32_f16(af[wm], bf[wn], acc[wm][wn], 0, 0, 0);
    __syncthreads();
  }
#pragma unroll
  for (int wm = 0; wm < WM; ++wm) {
#pragma unroll
    for (int wn = 0; wn < 2; ++wn) {
#pragma unroll
      for (int r = 0; r < 4; ++r) {
        int gm = gm0 + wr * (MT / 2) + wm * 16 + quad * 4 + r;
        int gn = n0 + wc * 32 + wn * 16 + ln;
        if (gm < M && gn < Ncols) {
          float v = alpha * acc[wm][wn][r];
          v += bias[gm];
          if (MODE == 1) {
            v = 1.f / (1.f + expf(-v));  // sigmoid
            C[(long long)gm * ldc + gn] = (fp16)v;
            if (gm < 64) {
              float h = (float)hIn[(long long)gm * 2048 + gn];
              rhOut[(long long)gm * 2048 + gn] = (fp16)(v * h);
            }
          } else {
            v = tanhf(v);
            float u = (float)uIn[(long long)(64 + gm) * NN + gn];
            long long ci = (long long)gm * ldc + gn;
            float h = (float)C[ci];
            C[ci] = (fp16)(u * h + (1.f - u) * v);
          }
        }
      }
    }
  }
}

// ---------- mfma3: all-b128 GEMM; M-split and N-split output mapping ----------
template <int MT, int NT>
__global__ __launch_bounds__(256) void mfma3(
    const fp16* __restrict__ A, int lda, long long zA, int aMsh, long long aMslab,
    const fp16* __restrict__ B, int ldb, long long zB,
    fp16* __restrict__ C, int ldc, long long zC, int cMsh, long long cMslab, int cNsh,
    long long cNslab,
    const fp16* __restrict__ S, long long zS, float beta,
    const float* __restrict__ rowBias, long long zRB,
    const float* __restrict__ s2T, int s2ld,
    int M, int Ncols, int K, float alpha, int act) {
  __shared__ fp16 As[MT][40];
  __shared__ fp16 Bs[NT][40];
  const int z = blockIdx.z;
  const int gm0 = blockIdx.x * MT, n0 = blockIdx.y * NT;
  A += (long long)z * zA;
  B += (long long)z * zB;
  C += (long long)z * zC;
  if (S) S += (long long)z * zS;
  const int tid = threadIdx.x;
  const int lane = tid & 63, wv = tid >> 6;
  const int wr = wv >> 1, wc = wv & 1;
  const int quad = lane >> 4, ln = lane & 15;
  const unsigned aMmask = (1u << aMsh) - 1u;
  const unsigned cMmask = (1u << cMsh) - 1u;
  const unsigned cNmask = (1u << cNsh) - 1u;
  constexpr int WM = MT / 32, WN = NT / 32;
  f32x4 acc[WM][WN];
#pragma unroll
  for (int i = 0; i < WM; ++i)
#pragma unroll
    for (int j = 0; j < WN; ++j) acc[i][j] = (f32x4){0.f, 0.f, 0.f, 0.f};

  for (int k0 = 0; k0 < K; k0 += 32) {
#pragma unroll
    for (int i = 0; i < MT / 64; ++i) {
      int c = tid + 256 * i;
      int row = c >> 2, seg = c & 3;
      int gm = gm0 + row;
      int kk0 = k0 + seg * 8;
      const fp16* src = A + ((long long)((unsigned)gm >> aMsh)) * aMslab +
                        (long long)(gm & aMmask) * lda + kk0;
      if (gm < M && kk0 + 8 <= K) {
        *(f16x8*)&As[row][seg * 8] = *(const f16x8*)src;
      } else {
#pragma unroll
        for (int j = 0; j < 8; ++j)
          As[row][seg * 8 + j] = (gm < M && kk0 + j < K) ? src[j] : (fp16)0.f;
      }
    }
#pragma unroll
    for (int i = 0; i < NT / 64; ++i) {
      int c = tid + 256 * i;
      int n = c >> 2, seg = c & 3;
      int gn = n0 + n;
      int kk0 = k0 + seg * 8;
      const fp16* src = B + (long long)gn * ldb + kk0;
      if (gn < Ncols && kk0 + 8 <= K) {
        *(f16x8*)&Bs[n][seg * 8] = *(const f16x8*)src;
      } else {
#pragma unroll
        for (int j = 0; j < 8; ++j)
          Bs[n][seg * 8 + j] = (gn < Ncols && kk0 + j < K) ? src[j] : (fp16)0.f;
      }
    }
    __syncthreads();
    f16x8 af[WM], bf[WN];
#pragma unroll
    for (int wm = 0; wm < WM; ++wm)
      af[wm] = *(const f16x8*)&As[wr * (MT / 2) + wm * 16 + ln][quad * 8];
#pragma unroll
    for (int wn = 0; wn < WN; ++wn)
      bf[wn] = *(const f16x8*)&Bs[wc * (NT / 2) + wn * 16 + ln][quad * 8];
#pragma unroll
    for (int wm = 0; wm < WM; ++wm)
#pragma unroll
      for (int wn = 0; wn < WN; ++wn)
        acc[wm][wn] =
            __builtin_amdgcn_mfma_f32_16x16x32_f16(af[wm], bf[wn], acc[wm][wn], 0, 0, 0);
    __syncthreads();
  }
#pragma unroll
  for (int wm = 0; wm < WM; ++wm) {
#pragma unroll
    for (int wn = 0; wn < WN; ++wn) {
#pragma unroll
      for (int r = 0; r < 4; ++r) {
        int gm = gm0 + wr * (MT / 2) + wm * 16 + quad * 4 + r;
        int gn = n0 + wc * (NT / 2) + wn * 16 + ln;
        if (gm < M && gn < Ncols) {
          float v = alpha * acc[wm][wn][r];
          if (rowBias) v += rowBias[(long long)z * zRB + gm];
          if (s2T) v += s2T[(long long)gn * s2ld + gm];
          long long ci = ((long long)((unsigned)gm >> cMsh)) * cMslab +
                         (long long)(gm & cMmask) * ldc +
                         ((long long)((unsigned)gn >> cNsh)) * cNslab + (gn & cNmask);
          if (S) v += beta * (float)S[ci];
          if (act == 1) v = fmaxf(v, 0.f);
          else if (act == 2) v = 1.f / (1.f + expf(-v));
          else if (act == 3) v = tanhf(v);
          C[ci] = (fp16)v;
        }
      }
    }
  }
}

// ---------- k_zxt: ZXt[d][n] = ZmovT@agh2^T (K=1024) + w2T@Tmat^T (K=64)
//            + teXb[z][d] + seX[n][d].  M=64, NT=128 (WN=4!), z in [0,96).
__global__ __launch_bounds__(256) void k_zxt(
    const fp16* __restrict__ A1, const fp16* __restrict__ B1,  // ZmovT, agh2
    const fp16* __restrict__ A2, const fp16* __restrict__ B2,  // w2T, Tmat
    fp16* __restrict__ C, const float* __restrict__ teXb, const float* __restrict__ seX) {
  __shared__ fp16 As[64][40];
  __shared__ fp16 Bs[128][40];
  const int z = blockIdx.z;
  const int n0 = blockIdx.y * 128;
  A1 += (long long)z * 64 * CC;
  B2 += (long long)z * NN * 64;
  C += (long long)z * 64 * NN;
  teXb += (long long)z * 64;
  const int tid = threadIdx.x;
  const int lane = tid & 63, wv = tid >> 6;
  const int wr = wv >> 1, wc = wv & 1;
  const int quad = lane >> 4, ln = lane & 15;
  f32x4 acc[2][4];
#pragma unroll
  for (int i = 0; i < 2; ++i)
#pragma unroll
    for (int j = 0; j < 4; ++j) acc[i][j] = (f32x4){0.f, 0.f, 0.f, 0.f};

  for (int k0 = 0; k0 < 1088; k0 += 32) {
    {
      int c = tid;
      int row = c >> 2, seg = c & 3;
      int kk0 = k0 + seg * 8;
      const fp16* src = (kk0 < 1024) ? (A1 + (long long)row * CC + kk0)
                                     : (A2 + (long long)row * 64 + (kk0 - 1024));
      *(f16x8*)&As[row][seg * 8] = *(const f16x8*)src;
    }
#pragma unroll
    for (int i = 0; i < 2; ++i) {
      int c = tid + 256 * i;
      int n = c >> 2, seg = c & 3;
      int gn = n0 + n;
      int kk0 = k0 + seg * 8;
      const fp16* src = (kk0 < 1024) ? (B1 + (long long)gn * CC + kk0)
                                     : (B2 + (long long)gn * 64 + (kk0 - 1024));
      if (gn < NN) {
        *(f16x8*)&Bs[n][seg * 8] = *(const f16x8*)src;
      } else {
#pragma unroll
        for (int j = 0; j < 8; ++j) Bs[n][seg * 8 + j] = (fp16)0.f;
      }
    }
    __syncthreads();
    f16x8 af[2], bf[4];
#pragma unroll
    for (int wm = 0; wm < 2; ++wm)
      af[wm] = *(const f16x8*)&As[wr * 32 + wm * 16 + ln][quad * 8];
#pragma unroll
    for (int wn = 0; wn < 4; ++wn)
      bf[wn] = *(const f16x8*)&Bs[wc * 64 + wn * 16 + ln][quad * 8];
#pragma unroll
    for (int wm = 0; wm < 2; ++wm)
#pragma unroll
      for (int wn = 0; wn < 4; ++wn)
        acc[wm][wn] =
            __builtin_amdgcn_mfma_f32_16x16x32_f16(af[wm], bf[wn], acc[wm][wn], 0, 0, 0);
    __syncthreads();
  }
#pragma unroll
  for (int wm = 0; wm < 2; ++wm)
#pragma unroll
    for (int wn = 0; wn < 4; ++wn)
#pragma unroll
      for (int r = 0; r < 4; ++r) {
        int gm = wr * 32 + wm * 16 + quad * 4 + r;
        int gn = n0 + wc * 64 + wn * 16 + ln;
        if (gn < NN) {
          float v = acc[wm][wn][r] + teXb[gm] + seX[(long long)gn * 64 + gm];
          C[(long long)gm * NN + gn] = (fp16)v;
        }
      }
}

// ---------- ConvLSTM conv as MFMA ----------
__global__ __launch_bounds__(256) void k_conv_mfma(
    const fp16* __restrict__ Zf, const fp16* __restrict__ h,
    const fp16* __restrict__ wcat, fp16* __restrict__ gates, int p) {
  __shared__ fp16 As[128][40];
  __shared__ fp16 Bs[64][40];
  const int gm0 = blockIdx.x * 128, n0 = blockIdx.y * 64;
  const int tid = threadIdx.x;
  const int lane = tid & 63, wv = tid >> 6;
  const int wr = wv >> 1, wc = wv & 1;
  const int quad = lane >> 4, ln = lane & 15;
  f32x4 acc[4][2];
#pragma unroll
  for (int i = 0; i < 4; ++i)
#pragma unroll
    for (int j = 0; j < 2; ++j) acc[i][j] = (f32x4){0.f, 0.f, 0.f, 0.f};

  for (int kb = 0; kb < 36; ++kb) {
    const int srcsel = kb >= 18;
    const int tap = (kb >> 1) % 9;
    const int half = kb & 1;
    const int dy = tap / 3 - 1, dx = tap % 3 - 1;
#pragma unroll
    for (int i = 0; i < 2; ++i) {
      int c = tid + 256 * i;
      int row = c >> 2, seg = c & 3;
      int m = gm0 + row;
      int b = m >> 10;
      int y = (m >> 5) & 31, x = m & 31;
      int yy = y + dy, xx = x + dx;
      bool valid = ((unsigned)yy < 32u) && ((unsigned)xx < 32u);
      f16x8 v;
      if (valid) {
        long long cell = ((long long)b << 10) + (yy << 5) + xx;
        const fp16* sp =
            srcsel ? (h + cell * 64)
                   : (Zf + ((((long long)(b * PP + p)) << 10) + (yy << 5) + xx) * 64);
        v = *(const f16x8*)(sp + half * 32 + seg * 8);
      } else {
#pragma unroll
        for (int j = 0; j < 8; ++j) v[j] = (fp16)0.f;
      }
      *(f16x8*)&As[row][seg * 8] = v;
    }
    {
      int kk = kb * 32 + (tid & 31);
      int ngrp = tid >> 5;
      int n = n0 + ngrp * 8;
      f16x8 v = *(const f16x8*)(wcat + (long long)kk * 256 + n);
#pragma unroll
      for (int j = 0; j < 8; ++j) Bs[ngrp * 8 + j][tid & 31] = v[j];
    }
    __syncthreads();
    f16x8 af[4], bf[2];
#pragma unroll
    for (int wm = 0; wm < 4; ++wm)
      af[wm] = *(const f16x8*)&As[wr * 64 + wm * 16 + ln][quad * 8];
#pragma unroll
    for (int wn = 0; wn < 2; ++wn)
      bf[wn] = *(const f16x8*)&Bs[wc * 32 + wn * 16 + ln][quad * 8];
#pragma unroll
    for (int wm = 0; wm < 4; ++wm)
#pragma unroll
      for (int wn = 0; wn < 2; ++wn)
        acc[wm][wn] =
            __builtin_amdgcn_mfma_f32_16x16x32_f16(af[wm], bf[wn], acc[wm][wn], 0, 0, 0);
    __syncthreads();
  }
#pragma unroll
  for (int wm = 0; wm < 4; ++wm)
#pragma unroll
    for (int wn = 0; wn < 2; ++wn)
#pragma unroll
      for (int r = 0; r < 4; ++r) {
        int gm = gm0 + wr * 64 + wm * 16 + quad * 4 + r;
        int gn = n0 + wc * 32 + wn * 16 + ln;
        gates[(long long)gm * 256 + gn] = (fp16)acc[wm][wn][r];
      }
}

__global__ void k_clstm_update(const fp16* __restrict__ gates, float* __restrict__ c,
                               fp16* __restrict__ h, fp16* __restrict__ ZclT, int p) {
  long long i = (long long)blockIdx.x * 256 + threadIdx.x;
  if (i >= (long long)BB * CC * 64) return;
  int d = (int)(i & 63);
  long long bc = i >> 6;
  int b = (int)(bc >> 10);
  int cell = (int)(bc & 1023);
  const fp16* g = gates + (((long long)b * CC) + cell) * 256;
  float gi = (float)g[d], gf = (float)g[64 + d], gg = (float)g[128 + d],
        go = (float)g[192 + d];
  float hs_f = fminf(fmaxf(0.2f * gf + 0.5f, 0.f), 1.f);
  float hs_i = fminf(fmaxf(0.2f * gi + 0.5f, 0.f), 1.f);
  float hs_o = fminf(fmaxf(0.2f * go + 0.5f, 0.f), 1.f);
  float cv = hs_f * c[i] + hs_i * tanhf(gg);
  c[i] = cv;
  float hv = hs_o * tanhf(cv);
  h[i] = (fp16)hv;
  ZclT[(((long long)(b * PP + p)) * 64 + d) * CC + cell] = (fp16)hv;
}

__global__ void k_tmat(const float* __restrict__ X, const float* __restrict__ w1,
                       const float* __restrict__ b1, fp16* __restrict__ T, long long nrows) {
  long long i = (long long)blockIdx.x * 256 + threadIdx.x;
  if (i >= nrows * 64) return;
  int j = (int)(i & 63);
  long long row = i >> 6;
  T[i] = (fp16)fmaxf(X[row] * w1[j] + b1[j], 0.f);
}

// ---------- DCGRU elementwise ----------
// fill U0 x-rows (0..63) only; h rows 64..127 are live storage
__global__ void k_u0x(const fp16* __restrict__ ZXt, fp16* __restrict__ U0, int p) {
  long long i = (long long)blockIdx.x * 256 + threadIdx.x;
  if (i >= (long long)BB * 64 * (NN / 8)) return;
  int n8 = (int)(i % (NN / 8));
  int c = (int)((i / (NN / 8)) & 63);
  int b = (int)(i / ((NN / 8) * 64));
  f16x8 v = *(const f16x8*)(ZXt + ((((long long)(b * PP + p)) * 64 + c) * NN) + n8 * 8);
  *(f16x8*)(U0 + ((long long)b * 192 + c) * 2048 + n8 * 8) = v;
}

__global__ void k_trT(const fp16* __restrict__ U0, float* __restrict__ htmp) {
  long long i = (long long)blockIdx.x * 256 + threadIdx.x;
  if (i >= (long long)BB * NN * 64) return;
  int d = (int)(i & 63);
  long long bn = i >> 6;
  int b = (int)(bn / NN);
  int n = (int)(bn % NN);
  htmp[i] = (float)U0[((long long)b * 192 + 64 + d) * 2048 + n];
}

__global__ void k_out(const float* __restrict__ Y, float* __restrict__ out) {
  int i = blockIdx.x * 256 + threadIdx.x;
  if (i >= BB * QQ * NN) return;
  int n = i % NN;
  int bq = i / NN;
  int b = bq / QQ, q = bq % QQ;
  out[i] = Y[((long long)b * NN + n) * 12 + q];
}

// ---------- host helpers ----------
template <typename TA, typename TB, typename TC>
static void launch_gemm(hipStream_t stream, const TA* A, int lda, long long sA,
                        const TB* Bm, int ldb, long long sB, TC* Cm, int ldc, long long sC,
                        const TC* S, long long sS, const float* bias, int M, int Nc, int K,
                        float alpha, float beta, int act, int batch) {
  dim3 g((M + 63) / 64, (Nc + 63) / 64, batch);
  gemm_t<TA, TB, TC><<<g, dim3(256), 0, stream>>>(A, lda, sA, Bm, ldb, sB, Cm, ldc, sC, S,
                                                  sS, bias, M, Nc, K, alpha, beta, act);
}

extern "C" void kernel_launch(void* const* d_in, const int* in_sizes, int n_in,
                              void* d_out, int out_size, void* d_ws, size_t ws_size,
                              hipStream_t stream) {
  char* base = (char*)d_ws;
  size_t off = 0;
  auto alloc_bytes = [&](size_t nb) -> char* {
    char* p = base + off;
    off += (nb + 255) & ~(size_t)255;
    return p;
  };
  auto allocf = [&](size_t n) -> float* { return (float*)alloc_bytes(n * 4); };
  auto alloch = [&](size_t n) -> fp16* { return (fp16*)alloc_bytes(n * 2); };

  const float* X = (const float*)d_in[0];
  const float* Z = (const float*)d_in[1];
  const int* TE = (const int*)d_in[2];
  const float* adj_gg = (const float*)d_in[3];
  const float* adj_gr = (const float*)d_in[4];
  const float* gumbel = (const float*)d_in[5];
  const float* se_x = (const float*)d_in[6];
  const float* se_z = (const float*)d_in[7];
  const float* movement = (const float*)d_in[8];
  auto W = [&](int i) { return (const float*)d_in[i]; };

  // ---- allocations ----
  fp16* wcat = alloch(1152 * 256);
  fp16* gwT = alloch(128 * 512);
  fp16* cwT = alloch(64 * 512);
  fp16* w2T = alloch(64 * 64);
  fp16* w2mT = alloch(64 * 64);
  float* dinv = allocf(NN);
  fp16* LMall = alloch((size_t)6144 * NN);
  fp16* mZh = alloch((size_t)CC * CC);
  fp16* agh2 = alloch((size_t)NN * CC);
  float* seZ = allocf(CC * 64);
  float* teZ = allocf(BB * PP * 64);
  float* seX = allocf(NN * 64);
  float* teXb = allocf(BB * PP * 64);
  float* mtmp = allocf(NN * 64);
  float* tetmp = allocf(BB * PP * 64);
  fp16* ruT = alloch((size_t)BB * 128 * NN);  // [b][128][2000]
  // pool (50.33MB): U slabs 4x[16][192][2048] fp16; aliases conv gates/chh/ccc + Zmix/ZmovT
  char* pool = alloc_bytes(50331648);
  fp16* Uall = (fp16*)pool;
  fp16* gates = (fp16*)pool;
  fp16* chh = (fp16*)(pool + 8388608);
  float* ccc = (float*)(pool + 12582912);
  fp16* Zmix = (fp16*)pool;
  fp16* ZmovT = (fp16*)(pool + 25165824);
  // zpool: Zf [bp][1024][64] then ZXt [bp][64][2000]
  fp16* zpool = alloch((size_t)BB * PP * NN * 64);
  fp16* Zf = zpool;
  fp16* ZXt = zpool;
  fp16* Zc = alloch((size_t)BB * PP * CC * 64);  // zf1 scratch -> ZclT -> Tmat -> head scratch

  if (off > ws_size) return;

  const long long uB = 192LL * 2048;
  const long long USL = 16LL * uB;
  fp16* Lh = LMall;
  fp16* M2h = LMall + 2048LL * NN;
  fp16* M3h = LMall + 4096LL * NN;

  // ---- precompute ----
  k_f2h<<<dim3(576), dim3(256), 0, stream>>>(wcat, W(39), 576 * 256);
  k_f2h<<<dim3(576), dim3(256), 0, stream>>>(wcat + 576 * 256, W(40), 576 * 256);
  k_gru_repackT<<<dim3(256), dim3(256), 0, stream>>>(gwT, W(41), 128);
  k_gru_repackT<<<dim3(128), dim3(256), 0, stream>>>(cwT, W(43), 64);
  k_w2T<<<dim3(16), dim3(256), 0, stream>>>(w2T, W(31));
  k_w2T<<<dim3(16), dim3(256), 0, stream>>>(w2mT, W(33));
  k_dinv<<<dim3(NN), dim3(256), 0, stream>>>(adj_gg, dinv);
  hipMemsetAsync(LMall, 0, (size_t)6144 * NN * 2, stream);
  k_L<<<dim3((NN * NN + 255) / 256), dim3(256), 0, stream>>>(adj_gg, dinv, Lh);
  mfma3<128, 128><<<dim3(16, 16, 1), dim3(256), 0, stream>>>(
      Lh, NN, 0LL, 31, 0LL, Lh, NN, 0LL, M2h, NN, 0LL, 31, 0LL, 31, 0LL,
      (const fp16*)nullptr, 0LL, 0.f, nullptr, 0LL, nullptr, 0, NN, NN, NN, 2.f, 0);
  k_subdiag<<<dim3((NN + 255) / 256), dim3(256), 0, stream>>>(M2h);
  mfma3<128, 128><<<dim3(16, 16, 1), dim3(256), 0, stream>>>(
      Lh, NN, 0LL, 31, 0LL, M2h, NN, 0LL, M3h, NN, 0LL, 31, 0LL, 31, 0LL,
      (const fp16*)Lh, 0LL, -1.f, nullptr, 0LL, nullptr, 0, NN, NN, NN, 2.f, 0);
  k_gumbel_softmax<<<dim3(CC), dim3(256), 0, stream>>>(movement, gumbel, mZh);
  k_f2h<<<dim3((NN * CC + 255) / 256), dim3(256), 0, stream>>>(agh2, adj_gr,
                                                               (long long)NN * CC);

  // ---- STEZ / STEX ----
  launch_gemm(stream, se_z, 64, 0LL, W(17), 64, 0LL, mtmp, 64, 0LL, (float*)nullptr, 0LL,
              W(18), CC, 64, 64, 1.f, 0.f, 1, 1);
  launch_gemm(stream, (const float*)mtmp, 64, 0LL, W(19), 64, 0LL, seZ, 64, 0LL,
              (float*)nullptr, 0LL, W(20), CC, 64, 64, 1.f, 0.f, 0, 1);
  k_te<<<dim3((BB * PP * 64 + 255) / 256), dim3(256), 0, stream>>>(TE, W(21), W(22), tetmp);
  launch_gemm(stream, (const float*)tetmp, 64, 0LL, W(23), 64, 0LL, teZ, 64, 0LL,
              (float*)nullptr, 0LL, W(24), BB * PP, 64, 64, 1.f, 0.f, 0, 1);
  launch_gemm(stream, se_x, 64, 0LL, W(9), 64, 0LL, mtmp, 64, 0LL, (float*)nullptr, 0LL,
              W(10), NN, 64, 64, 1.f, 0.f, 1, 1);
  launch_gemm(stream, (const float*)mtmp, 64, 0LL, W(11), 64, 0LL, seX, 64, 0LL,
              (float*)nullptr, 0LL, W(12), NN, 64, 64, 1.f, 0.f, 0, 1);
  k_te<<<dim3((BB * PP * 64 + 255) / 256), dim3(256), 0, stream>>>(TE, W(13), W(14), tetmp);
  launch_gemm(stream, (const float*)tetmp, 64, 0LL, W(15), 64, 0LL, teXb, 64, 0LL,
              (float*)nullptr, 0LL, W(16), BB * PP, 64, 64, 1.f, 0.f, 0, 1);
  k_addb<<<dim3((BB * PP * 64 + 255) / 256), dim3(256), 0, stream>>>(teXb, W(32),
                                                                     BB * PP * 64);

  // ---- Zf = mlp2(Z) + STEZ ----
  long long nZ = (long long)BB * PP * CC * 64;
  k_zf1<<<dim3((int)((nZ + 255) / 256)), dim3(256), 0, stream>>>(Z, W(25), W(26), Zc);
  launch_gemm(stream, (const fp16*)Zc, 64, 0LL, W(27), 64, 0LL, Zf, 64, 0LL,
              (fp16*)nullptr, 0LL, W(28), BB * PP * CC, 64, 64, 1.f, 0.f, 0, 1);
  k_add_stez<<<dim3((int)((nZ + 255) / 256)), dim3(256), 0, stream>>>(Zf, seZ, teZ);

  // ---- ConvLSTM (writes ZclT into Zc) ----
  hipMemsetAsync(chh, 0, (size_t)BB * CC * 64 * 2, stream);
  hipMemsetAsync(ccc, 0, (size_t)BB * CC * 64 * 4, stream);
  for (int p = 0; p < PP; ++p) {
    k_conv_mfma<<<dim3(BB * CC / 128, 4), dim3(256), 0, stream>>>(Zf, chh, wcat, gates, p);
    k_clstm_update<<<dim3((int)(((long long)BB * CC * 64 + 255) / 256)), dim3(256), 0,
                     stream>>>(gates, ccc, chh, Zc, p);
  }

  // ---- movement m1/m2 ----
  mfma3<128, 64><<<dim3(8, 1, 192), dim3(256), 0, stream>>>(
      mZh, CC, 0LL, 31, 0LL, (const fp16*)Zc, CC, (long long)64 * CC, Zmix, 64,
      (long long)CC * 64, 31, 0LL, 31, 0LL, (const fp16*)nullptr, 0LL, 0.f, nullptr, 0LL,
      nullptr, 0, CC, 64, CC, 1.f, 0);
  mfma3<64, 128><<<dim3(1, 8, 192), dim3(256), 0, stream>>>(
      w2mT, 64, 0LL, 31, 0LL, Zmix, 64, (long long)CC * 64, ZmovT, CC, (long long)64 * CC,
      31, 0LL, 31, 0LL, (const fp16*)nullptr, 0LL, 0.f, W(34), 0LL, nullptr, 0, 64, CC, 64,
      1.f, 1);

  // ---- merged m3+Tmat (fixed WN=4 k_zxt; two z-halves, Tmat in dead Zc) ----
  fp16* Tmat = Zc;
  for (int half = 0; half < 2; ++half) {
    long long z0 = 96LL * half;
    k_tmat<<<dim3((int)((96LL * NN * 64 + 255) / 256)), dim3(256), 0, stream>>>(
        X + z0 * NN, W(29), W(30), Tmat, 96LL * NN);
    k_zxt<<<dim3(1, 16, 96), dim3(256), 0, stream>>>(
        ZmovT + z0 * 64 * CC, agh2, w2T, Tmat, ZXt + z0 * 64 * NN, teXb + z0 * 64, seX);
  }

  // ---- DCGRU (fused epilogues; h lives in U0 rows 64..127) ----
  fp16* U0 = Uall;
  fp16* U1 = Uall + USL;
  hipMemsetAsync(U0, 0, (size_t)USL * 2, stream);  // zero slab 0 (h rows start at 0)
  const long long nU0x = (long long)BB * 64 * (NN / 8);
  for (int p = 0; p < PP; ++p) {
    // U0 x-rows <- ZXt_p ; h rows 64..127 hold h_{p-1}
    k_u0x<<<dim3((int)((nU0x + 255) / 256)), dim3(256), 0, stream>>>(ZXt, U0, p);
    // gate+h chain: [T1|T2|T3](rows 0..127) = U0[x|h] @ [L|M2|M3]
    mfma3<128, 128><<<dim3(16, 48, 1), dim3(256), 0, stream>>>(
        U0, 2048, 0LL, 7, uB, LMall, NN, 0LL, U1, 2048, 0LL, 7, uB, 11, USL,
        (const fp16*)nullptr, 0LL, 0.f, nullptr, 0LL, nullptr, 0, 2048, 6144, NN, 1.f, 0);
    // ruT = sigmoid(gwT @ chebs); epilogue writes rh = r*h into U0 rows 128..191
    mfma2<128, 1><<<dim3(1, 32, BB), dim3(256), 0, stream>>>(
        gwT, 512, Uall, 2048, uB, 7, USL, 0, ruT, NN, (long long)128 * NN, W(42),
        U0 + 128 * 2048, U0 + 64 * 2048, uB, (const fp16*)nullptr, 0LL, 128, NN, 512, 1.f);
    // cand rh chain -> U1..U3 rows 128..191
    mfma3<128, 64><<<dim3(8, 96, 1), dim3(256), 0, stream>>>(
        U0 + 128 * 2048, 2048, 0LL, 6, uB, LMall, NN, 0LL, U1 + 128 * 2048, 2048, 0LL, 6,
        uB, 11, USL, (const fp16*)nullptr, 0LL, 0.f, nullptr, 0LL, nullptr, 0, 1024, 6144,
        NN, 1.f, 0);
    // cnd GEMM; epilogue does h' = u*h + (1-u)*tanh(v) in place in U0 rows 64..127
    mfma2<64, 2><<<dim3(1, 32, BB), dim3(256), 0, stream>>>(
        cwT, 512, Uall, 2048, uB, 7, USL, 64, U0 + 64 * 2048, 2048, uB, W(44),
        (fp16*)nullptr, (const fp16*)nullptr, 0LL, (const fp16*)ruT, (long long)128 * NN,
        64, NN, 512, 1.f);
  }

  // ---- output head (all scratch in dead Zc; U0 untouched until read) ----
  float* htmp = (float*)Zc;                       // 8.19 MB
  float* out1 = (float*)(Zc + 5120000);           // byte 10.24 MB, 8.19 MB
  float* out2 = (float*)(Zc + 10240000);          // byte 20.48 MB, 1.54 MB
  k_trT<<<dim3((int)(((long long)BB * NN * 64 + 255) / 256)), dim3(256), 0, stream>>>(U0,
                                                                                      htmp);
  launch_gemm(stream, (const float*)htmp, 64, 0LL, W(35), 64, 0LL, out1, 64, 0LL,
              (float*)nullptr, 0LL, W(36), BB * NN, 64, 64, 1.f, 0.f, 1, 1);
  launch_gemm(stream, (const float*)out1, 64, 0LL, W(37), 12, 0LL, out2, 12, 0LL,
              (float*)nullptr, 0LL, W(38), BB * NN, 12, 64, 1.f, 0.f, 0, 1);
  k_out<<<dim3((BB * QQ * NN + 255) / 256), dim3(256), 0, stream>>>(out2, (float*)d_out);
}